// Round 1
// baseline (184.402 us; speedup 1.0000x reference)
//
#include <hip/hip_runtime.h>
#include <hip/hip_bf16.h>
#include <cstdint>
#include <cstddef>

// Problem dims (fixed): B=4, S=2048, D=512, H=8, HD=64, M = B*S = 8192
#define S_LEN 2048
#define D_DIM 512
#define NHEAD 8
#define HDIM  64

typedef __attribute__((ext_vector_type(8))) __bf16 b8;   // MFMA A/B fragment (4 VGPRs)
typedef __attribute__((ext_vector_type(4))) __bf16 b4;   // 8-byte vector
typedef __attribute__((ext_vector_type(4))) float  f4;   // MFMA C/D fragment

#define AS_GLOBAL __attribute__((address_space(1)))
#define AS_LDS    __attribute__((address_space(3)))

__device__ __forceinline__ void load_lds16(const void* g, void* l) {
  __builtin_amdgcn_global_load_lds((const AS_GLOBAL void*)g, (AS_LDS void*)l, 16, 0, 0);
}

__device__ __forceinline__ f4 mfma16(b8 a, b8 b, f4 c) {
  return __builtin_amdgcn_mfma_f32_16x16x32_bf16(a, b, c, 0, 0, 0);
}

// ===================== fp32 -> bf16 conversion =====================
__global__ __launch_bounds__(256) void cvt_kernel(const float* __restrict__ in,
                                                  __bf16* __restrict__ out) {
  int i = (blockIdx.x * 256 + threadIdx.x) * 4;
  float4 v = *reinterpret_cast<const float4*>(in + i);
  b4 o;
  o.x = (__bf16)v.x; o.y = (__bf16)v.y; o.z = (__bf16)v.z; o.w = (__bf16)v.w;
  *reinterpret_cast<b4*>(out + i) = o;
}

__global__ __launch_bounds__(256) void cvt_w_kernel(const float* __restrict__ w0, const float* __restrict__ w1,
                                                    const float* __restrict__ w2, const float* __restrict__ w3,
                                                    __bf16* o0, __bf16* o1, __bf16* o2, __bf16* o3) {
  const float* in = blockIdx.y == 0 ? w0 : blockIdx.y == 1 ? w1 : blockIdx.y == 2 ? w2 : w3;
  __bf16* out     = blockIdx.y == 0 ? o0 : blockIdx.y == 1 ? o1 : blockIdx.y == 2 ? o2 : o3;
  int i = (blockIdx.x * 256 + threadIdx.x) * 4;
  float4 v = *reinterpret_cast<const float4*>(in + i);
  b4 o;
  o.x = (__bf16)v.x; o.y = (__bf16)v.y; o.z = (__bf16)v.z; o.w = (__bf16)v.w;
  *reinterpret_cast<b4*>(out + i) = o;
}

// ===================== GEMM core: C(128x128) = A * W^T =====================
// A: [M,512] bf16 row-major, W: [N,512] bf16 row-major (NT GEMM -> both
// fragments are contiguous ds_read_b128). 256 threads = 4 waves (2x2 of 64x64).
__device__ __forceinline__ void gemm_core(const __bf16* __restrict__ A, const __bf16* __restrict__ W,
                                          int m0, int n0, __bf16* As, __bf16* Bs, f4 acc[4][4]) {
  const int t = threadIdx.x;
  const int lane = t & 63;
  const int w = t >> 6, wr = w >> 1, wc = w & 1;
  const f4 zero = {0.f, 0.f, 0.f, 0.f};
  #pragma unroll
  for (int mi = 0; mi < 4; ++mi)
    #pragma unroll
    for (int ni = 0; ni < 4; ++ni) acc[mi][ni] = zero;

  const char* Ab = (const char*)A;
  const char* Wb = (const char*)W;
  for (int kt = 0; kt < 512; kt += 64) {
    __syncthreads();  // prev-iter LDS reads finished before overwrite
    #pragma unroll
    for (int i = 0; i < 4; ++i) {
      int o = i * 4096 + t * 16;   // byte offset in 16 KiB tile
      int row = o >> 7, cb = o & 127;
      load_lds16(Ab + ((size_t)(m0 + row) * 512 + kt) * 2 + cb, (char*)As + o);
      load_lds16(Wb + ((size_t)(n0 + row) * 512 + kt) * 2 + cb, (char*)Bs + o);
    }
    __syncthreads();  // staging complete (vmcnt drained by barrier semantics)
    #pragma unroll
    for (int kk = 0; kk < 2; ++kk) {
      b8 af[4], bf[4];
      #pragma unroll
      for (int mi = 0; mi < 4; ++mi)
        af[mi] = *reinterpret_cast<const b8*>(&As[(wr * 64 + mi * 16 + (lane & 15)) * 64 + kk * 32 + ((lane >> 4) << 3)]);
      #pragma unroll
      for (int ni = 0; ni < 4; ++ni)
        bf[ni] = *reinterpret_cast<const b8*>(&Bs[(wc * 64 + ni * 16 + (lane & 15)) * 64 + kk * 32 + ((lane >> 4) << 3)]);
      #pragma unroll
      for (int mi = 0; mi < 4; ++mi)
        #pragma unroll
        for (int ni = 0; ni < 4; ++ni)
          acc[mi][ni] = mfma16(af[mi], bf[ni], acc[mi][ni]);
    }
  }
}

// ===================== QKV projection =====================
// grid (64, 4, 3); z picks {Wq,Wk,Wv}. Writes [B,H,S,HD] bf16.
__global__ __launch_bounds__(256) void gemm_qkv_kernel(
    const __bf16* __restrict__ xb,
    const __bf16* __restrict__ wq, const __bf16* __restrict__ wk, const __bf16* __restrict__ wv,
    const float* __restrict__ bq, const float* __restrict__ bk, const float* __restrict__ bv,
    __bf16* Qo, __bf16* Ko, __bf16* Vo) {
  __shared__ __bf16 As[128 * 64];
  __shared__ __bf16 Bs[128 * 64];
  int z = blockIdx.z;
  const __bf16* W = z == 0 ? wq : (z == 1 ? wk : wv);
  const float* bias = z == 0 ? bq : (z == 1 ? bk : bv);
  __bf16* out = z == 0 ? Qo : (z == 1 ? Ko : Vo);
  int m0 = blockIdx.x * 128, n0 = blockIdx.y * 128;
  f4 acc[4][4];
  gemm_core(xb, W, m0, n0, As, Bs, acc);
  int t = threadIdx.x, lane = t & 63, w = t >> 6, wr = w >> 1, wc = w & 1;
  #pragma unroll
  for (int mi = 0; mi < 4; ++mi)
    #pragma unroll
    for (int ni = 0; ni < 4; ++ni)
      #pragma unroll
      for (int r = 0; r < 4; ++r) {
        int m = m0 + wr * 64 + mi * 16 + ((lane >> 4) << 2) + r;  // C row
        int n = n0 + wc * 64 + ni * 16 + (lane & 15);             // C col
        float v = acc[mi][ni][r] + bias[n];
        int b = m >> 11, s = m & 2047, h = n >> 6, hd = n & 63;
        out[(((size_t)(b * NHEAD + h)) * S_LEN + s) * HDIM + hd] = (__bf16)v;
      }
}

// ===================== output projection =====================
__global__ __launch_bounds__(256) void gemm_o_kernel(const __bf16* __restrict__ ctx,
                                                     const __bf16* __restrict__ wo,
                                                     const float* __restrict__ bo,
                                                     float* __restrict__ out) {
  __shared__ __bf16 As[128 * 64];
  __shared__ __bf16 Bs[128 * 64];
  int m0 = blockIdx.x * 128, n0 = blockIdx.y * 128;
  f4 acc[4][4];
  gemm_core(ctx, wo, m0, n0, As, Bs, acc);
  int t = threadIdx.x, lane = t & 63, w = t >> 6, wr = w >> 1, wc = w & 1;
  #pragma unroll
  for (int mi = 0; mi < 4; ++mi)
    #pragma unroll
    for (int ni = 0; ni < 4; ++ni)
      #pragma unroll
      for (int r = 0; r < 4; ++r) {
        int m = m0 + wr * 64 + mi * 16 + ((lane >> 4) << 2) + r;
        int n = n0 + wc * 64 + ni * 16 + (lane & 15);
        out[(size_t)m * D_DIM + n] = acc[mi][ni][r] + bo[n];
      }
}

// ===================== V transpose: [B,H,S,HD] -> [B,H,HD,S] =====================
__global__ __launch_bounds__(256) void transpose_v_kernel(const __bf16* __restrict__ V,
                                                          __bf16* __restrict__ Vt) {
  __shared__ __bf16 tile[64][72];  // pad 72 keeps 16B row alignment, breaks bank aliasing
  int bh = blockIdx.y, s0 = blockIdx.x * 64;
  const __bf16* Vp = V + (size_t)bh * S_LEN * HDIM;
  __bf16* Vtp = Vt + (size_t)bh * HDIM * S_LEN;
  int t = threadIdx.x;
  #pragma unroll
  for (int i = 0; i < 4; ++i) {
    int q = t + i * 256;              // quad index 0..1023
    int row = q >> 4, c4 = (q & 15) * 4;
    b4 v = *reinterpret_cast<const b4*>(&Vp[(size_t)(s0 + row) * HDIM + c4]);
    *reinterpret_cast<b4*>(&tile[row][c4]) = v;
  }
  __syncthreads();
  #pragma unroll
  for (int i = 0; i < 4; ++i) {
    int q = t + i * 256;
    int d = q >> 4, s4 = (q & 15) * 4;
    b4 v;
    v.x = tile[s4 + 0][d]; v.y = tile[s4 + 1][d];
    v.z = tile[s4 + 2][d]; v.w = tile[s4 + 3][d];
    *reinterpret_cast<b4*>(&Vtp[(size_t)d * S_LEN + s0 + s4]) = v;
  }
}

// ===================== flash attention =====================
// grid (S/64, B*H), 256 threads = 4 waves; each wave owns 16 q-rows.
// Q,K: [B,H,S,HD] bf16; Vt: [B,H,HD,S] bf16; ctx out: [B,S,D] bf16.
__global__ __launch_bounds__(256) void attn_kernel(const __bf16* __restrict__ Q,
                                                   const __bf16* __restrict__ K,
                                                   const __bf16* __restrict__ Vt,
                                                   __bf16* __restrict__ ctx) {
  __shared__ __bf16 Ks[64 * 64];      // [kv][d]
  __shared__ __bf16 Vs[64 * 64];      // [d][kv]
  __shared__ __bf16 Ps[4][16 * 64];   // per-wave P tile [qi][kv]
  int t = threadIdx.x, lane = t & 63, w = t >> 6;
  int bh = blockIdx.y, b = bh >> 3, h = bh & 7;
  int qw = blockIdx.x * 64 + w * 16;  // wave's first q row
  const __bf16* Qp = Q + (size_t)bh * S_LEN * HDIM;
  const __bf16* Kp = K + (size_t)bh * S_LEN * HDIM;
  const __bf16* Vp = Vt + (size_t)bh * HDIM * S_LEN;

  // Q fragments held in registers for the whole kernel (A-layout: row=lane&15)
  b8 qf[2];
  #pragma unroll
  for (int kk = 0; kk < 2; ++kk)
    qf[kk] = *reinterpret_cast<const b8*>(&Qp[(size_t)(qw + (lane & 15)) * HDIM + kk * 32 + ((lane >> 4) << 3)]);

  const f4 zero = {0.f, 0.f, 0.f, 0.f};
  f4 oacc[4];
  #pragma unroll
  for (int df = 0; df < 4; ++df) oacc[df] = zero;
  float mr[4], lr[4];
  #pragma unroll
  for (int r = 0; r < 4; ++r) { mr[r] = -1e30f; lr[r] = 0.f; }
  const float scale = 0.125f;  // 1/sqrt(64)

  for (int kt = 0; kt < S_LEN; kt += 64) {
    __syncthreads();  // everyone done reading prev K/V tiles
    #pragma unroll
    for (int i = 0; i < 2; ++i) {
      int o = i * 4096 + t * 16;
      int row = o >> 7, cb = o & 127;
      load_lds16((const char*)Kp + (size_t)(kt + row) * 128 + cb, (char*)Ks + o);
      load_lds16((const char*)Vp + (size_t)row * (S_LEN * 2) + (size_t)kt * 2 + cb, (char*)Vs + o);
    }
    __syncthreads();

    // S = Q K^T (rows=q via C-layout, cols=kv)
    f4 sf[4];
    #pragma unroll
    for (int nf = 0; nf < 4; ++nf) {
      sf[nf] = zero;
      #pragma unroll
      for (int kk = 0; kk < 2; ++kk) {
        b8 kf = *reinterpret_cast<const b8*>(&Ks[(nf * 16 + (lane & 15)) * 64 + kk * 32 + ((lane >> 4) << 3)]);
        sf[nf] = mfma16(qf[kk], kf, sf[nf]);
      }
    }
    #pragma unroll
    for (int nf = 0; nf < 4; ++nf) sf[nf] *= scale;

    // online softmax: row r of this lane's group = (lane>>4)*4 + r
    float alpha[4];
    #pragma unroll
    for (int r = 0; r < 4; ++r) {
      float mx = fmaxf(fmaxf(sf[0][r], sf[1][r]), fmaxf(sf[2][r], sf[3][r]));
      #pragma unroll
      for (int off = 8; off >= 1; off >>= 1) mx = fmaxf(mx, __shfl_xor(mx, off, 16));
      float mn = fmaxf(mr[r], mx);
      alpha[r] = __expf(mr[r] - mn);
      mr[r] = mn;
      lr[r] *= alpha[r];
    }
    // P = exp(S - m), accumulate per-lane partial row sums, spill P to LDS (bf16)
    #pragma unroll
    for (int nf = 0; nf < 4; ++nf)
      #pragma unroll
      for (int r = 0; r < 4; ++r) {
        float p = __expf(sf[nf][r] - mr[r]);
        lr[r] += p;
        Ps[w][(((lane >> 4) << 2) + r) * 64 + nf * 16 + (lane & 15)] = (__bf16)p;
      }
    // rescale running context
    #pragma unroll
    for (int df = 0; df < 4; ++df)
      #pragma unroll
      for (int r = 0; r < 4; ++r) oacc[df][r] *= alpha[r];

    // PV: A = P (re-read in A-layout from wave-private LDS; same-wave DS ops are ordered)
    #pragma unroll
    for (int df = 0; df < 4; ++df) {
      #pragma unroll
      for (int ks = 0; ks < 2; ++ks) {
        b8 pf = *reinterpret_cast<const b8*>(&Ps[w][(lane & 15) * 64 + ks * 32 + ((lane >> 4) << 3)]);
        b8 vf = *reinterpret_cast<const b8*>(&Vs[(df * 16 + (lane & 15)) * 64 + ks * 32 + ((lane >> 4) << 3)]);
        oacc[df] = mfma16(pf, vf, oacc[df]);
      }
    }
  }

  // finish: reduce row sums across the 16-lane group, normalize, write ctx [B,S,D]
  #pragma unroll
  for (int r = 0; r < 4; ++r)
    #pragma unroll
    for (int off = 8; off >= 1; off >>= 1) lr[r] += __shfl_xor(lr[r], off, 16);

  __bf16* cp = ctx + (size_t)b * S_LEN * D_DIM + (size_t)h * HDIM;
  #pragma unroll
  for (int df = 0; df < 4; ++df)
    #pragma unroll
    for (int r = 0; r < 4; ++r) {
      int q = qw + ((lane >> 4) << 2) + r;
      int d = df * 16 + (lane & 15);
      cp[(size_t)q * D_DIM + d] = (__bf16)(oacc[df][r] / lr[r]);
    }
}

// ===================== launch =====================
extern "C" void kernel_launch(void* const* d_in, const int* in_sizes, int n_in,
                              void* d_out, int out_size, void* d_ws, size_t ws_size,
                              hipStream_t stream) {
  const float* x  = (const float*)d_in[0];
  const float* Wq = (const float*)d_in[1];
  const float* bq = (const float*)d_in[2];
  const float* Wk = (const float*)d_in[3];
  const float* bk = (const float*)d_in[4];
  const float* Wv = (const float*)d_in[5];
  const float* bv = (const float*)d_in[6];
  const float* Wo = (const float*)d_in[7];
  const float* bo = (const float*)d_in[8];
  float* out = (float*)d_out;

  // workspace layout (bf16 elements); ctx reuses the x-bf16 slot (dead after QKV)
  char* ws = (char*)d_ws;
  __bf16* xb   = (__bf16*)(ws);                               // 8192*512
  __bf16* wqb  = xb  + 4194304;                               // 512*512
  __bf16* wkb  = wqb + 262144;
  __bf16* wvb  = wkb + 262144;
  __bf16* wob  = wvb + 262144;
  __bf16* Qb   = wob + 262144;                                // 4*8*2048*64
  __bf16* Kb   = Qb  + 4194304;
  __bf16* Vb   = Kb  + 4194304;
  __bf16* Vtb  = Vb  + 4194304;
  __bf16* ctxb = xb;  // reuse

  cvt_kernel<<<dim3(4096), dim3(256), 0, stream>>>(x, xb);
  cvt_w_kernel<<<dim3(256, 4), dim3(256), 0, stream>>>(Wq, Wk, Wv, Wo, wqb, wkb, wvb, wob);
  gemm_qkv_kernel<<<dim3(64, 4, 3), dim3(256), 0, stream>>>(xb, wqb, wkb, wvb, bq, bk, bv, Qb, Kb, Vb);
  transpose_v_kernel<<<dim3(32, 32), dim3(256), 0, stream>>>(Vb, Vtb);
  attn_kernel<<<dim3(32, 32), dim3(256), 0, stream>>>(Qb, Kb, Vtb, ctxb);
  gemm_o_kernel<<<dim3(64, 4), dim3(256), 0, stream>>>(ctxb, wob, bo, out);
}

// Round 2
// 146.015 us; speedup vs baseline: 1.2629x; 1.2629x over previous
//
#include <hip/hip_runtime.h>
#include <hip/hip_bf16.h>
#include <cstdint>
#include <cstddef>

// Problem dims (fixed): B=4, S=2048, D=512, H=8, HD=64, M = B*S = 8192
#define S_LEN 2048
#define D_DIM 512
#define NHEAD 8
#define HDIM  64

typedef __attribute__((ext_vector_type(8))) __bf16 b8;   // MFMA A/B fragment (4 VGPRs)
typedef __attribute__((ext_vector_type(4))) __bf16 b4;   // 8-byte vector
typedef __attribute__((ext_vector_type(4))) float  f4;   // MFMA C/D fragment

#define AS_GLOBAL __attribute__((address_space(1)))
#define AS_LDS    __attribute__((address_space(3)))

__device__ __forceinline__ void load_lds16(const void* g, void* l) {
  __builtin_amdgcn_global_load_lds((const AS_GLOBAL void*)g, (AS_LDS void*)l, 16, 0, 0);
}

__device__ __forceinline__ f4 mfma16(b8 a, b8 b, f4 c) {
  return __builtin_amdgcn_mfma_f32_16x16x32_bf16(a, b, c, 0, 0, 0);
}

// Swizzled read from an LDS tile with 128-byte rows. Physical byte =
// row*128 + (bytecol ^ ((row&7)<<4)); staging pre-applies the same XOR to the
// global source column so logical data lands in the right slot (involution).
__device__ __forceinline__ b8 lds_frag(const __bf16* base, int row, int bc) {
  return *reinterpret_cast<const b8*>((const char*)base + row * 128 + (bc ^ ((row & 7) << 4)));
}

// ===================== fp32 -> bf16 conversion =====================
__global__ __launch_bounds__(256) void cvt_kernel(const float* __restrict__ in,
                                                  __bf16* __restrict__ out) {
  int i = (blockIdx.x * 256 + threadIdx.x) * 4;
  float4 v = *reinterpret_cast<const float4*>(in + i);
  b4 o;
  o.x = (__bf16)v.x; o.y = (__bf16)v.y; o.z = (__bf16)v.z; o.w = (__bf16)v.w;
  *reinterpret_cast<b4*>(out + i) = o;
}

__global__ __launch_bounds__(256) void cvt_w_kernel(const float* __restrict__ w0, const float* __restrict__ w1,
                                                    const float* __restrict__ w2, const float* __restrict__ w3,
                                                    __bf16* o0, __bf16* o1, __bf16* o2, __bf16* o3) {
  const float* in = blockIdx.y == 0 ? w0 : blockIdx.y == 1 ? w1 : blockIdx.y == 2 ? w2 : w3;
  __bf16* out     = blockIdx.y == 0 ? o0 : blockIdx.y == 1 ? o1 : blockIdx.y == 2 ? o2 : o3;
  int i = (blockIdx.x * 256 + threadIdx.x) * 4;
  float4 v = *reinterpret_cast<const float4*>(in + i);
  b4 o;
  o.x = (__bf16)v.x; o.y = (__bf16)v.y; o.z = (__bf16)v.z; o.w = (__bf16)v.w;
  *reinterpret_cast<b4*>(out + i) = o;
}

// ===================== GEMM core: C(128x128) = A * W^T =====================
// A: [M,512] bf16 row-major, W: [N,512] bf16 row-major (NT GEMM -> both
// fragments are contiguous ds_read_b128). 256 threads = 4 waves (2x2 of 64x64).
__device__ __forceinline__ void gemm_core(const __bf16* __restrict__ A, const __bf16* __restrict__ W,
                                          int m0, int n0, __bf16* As, __bf16* Bs, f4 acc[4][4]) {
  const int t = threadIdx.x;
  const int lane = t & 63;
  const int w = t >> 6, wr = w >> 1, wc = w & 1;
  const f4 zero = {0.f, 0.f, 0.f, 0.f};
  #pragma unroll
  for (int mi = 0; mi < 4; ++mi)
    #pragma unroll
    for (int ni = 0; ni < 4; ++ni) acc[mi][ni] = zero;

  const char* Ab = (const char*)A;
  const char* Wb = (const char*)W;
  for (int kt = 0; kt < 512; kt += 64) {
    __syncthreads();  // prev-iter LDS reads finished before overwrite
    #pragma unroll
    for (int i = 0; i < 4; ++i) {
      int o = i * 4096 + t * 16;   // byte offset in 16 KiB tile
      int row = o >> 7, cb = o & 127;
      int scb = cb ^ ((row & 7) << 4);   // inverse-swizzled source column
      load_lds16(Ab + ((size_t)(m0 + row) * 512 + kt) * 2 + scb, (char*)As + o);
      load_lds16(Wb + ((size_t)(n0 + row) * 512 + kt) * 2 + scb, (char*)Bs + o);
    }
    __syncthreads();  // staging complete (vmcnt drained by barrier semantics)
    #pragma unroll
    for (int kk = 0; kk < 2; ++kk) {
      b8 af[4], bf[4];
      #pragma unroll
      for (int mi = 0; mi < 4; ++mi)
        af[mi] = lds_frag(As, wr * 64 + mi * 16 + (lane & 15), kk * 64 + ((lane >> 4) << 4));
      #pragma unroll
      for (int ni = 0; ni < 4; ++ni)
        bf[ni] = lds_frag(Bs, wc * 64 + ni * 16 + (lane & 15), kk * 64 + ((lane >> 4) << 4));
      #pragma unroll
      for (int mi = 0; mi < 4; ++mi)
        #pragma unroll
        for (int ni = 0; ni < 4; ++ni)
          acc[mi][ni] = mfma16(af[mi], bf[ni], acc[mi][ni]);
    }
  }
}

// ===================== QKV projection =====================
// grid (64, 4, 3); z picks {Wq,Wk,Wv}. Writes [B,H,S,HD] bf16.
__global__ __launch_bounds__(256) void gemm_qkv_kernel(
    const __bf16* __restrict__ xb,
    const __bf16* __restrict__ wq, const __bf16* __restrict__ wk, const __bf16* __restrict__ wv,
    const float* __restrict__ bq, const float* __restrict__ bk, const float* __restrict__ bv,
    __bf16* Qo, __bf16* Ko, __bf16* Vo) {
  __shared__ __bf16 As[128 * 64];
  __shared__ __bf16 Bs[128 * 64];
  int z = blockIdx.z;
  const __bf16* W = z == 0 ? wq : (z == 1 ? wk : wv);
  const float* bias = z == 0 ? bq : (z == 1 ? bk : bv);
  __bf16* out = z == 0 ? Qo : (z == 1 ? Ko : Vo);
  int m0 = blockIdx.x * 128, n0 = blockIdx.y * 128;
  f4 acc[4][4];
  gemm_core(xb, W, m0, n0, As, Bs, acc);
  int t = threadIdx.x, lane = t & 63, w = t >> 6, wr = w >> 1, wc = w & 1;
  #pragma unroll
  for (int mi = 0; mi < 4; ++mi)
    #pragma unroll
    for (int ni = 0; ni < 4; ++ni)
      #pragma unroll
      for (int r = 0; r < 4; ++r) {
        int m = m0 + wr * 64 + mi * 16 + ((lane >> 4) << 2) + r;  // C row
        int n = n0 + wc * 64 + ni * 16 + (lane & 15);             // C col
        float v = acc[mi][ni][r] + bias[n];
        int b = m >> 11, s = m & 2047, h = n >> 6, hd = n & 63;
        out[(((size_t)(b * NHEAD + h)) * S_LEN + s) * HDIM + hd] = (__bf16)v;
      }
}

// ===================== output projection =====================
__global__ __launch_bounds__(256) void gemm_o_kernel(const __bf16* __restrict__ ctx,
                                                     const __bf16* __restrict__ wo,
                                                     const float* __restrict__ bo,
                                                     float* __restrict__ out) {
  __shared__ __bf16 As[128 * 64];
  __shared__ __bf16 Bs[128 * 64];
  int m0 = blockIdx.x * 128, n0 = blockIdx.y * 128;
  f4 acc[4][4];
  gemm_core(ctx, wo, m0, n0, As, Bs, acc);
  int t = threadIdx.x, lane = t & 63, w = t >> 6, wr = w >> 1, wc = w & 1;
  #pragma unroll
  for (int mi = 0; mi < 4; ++mi)
    #pragma unroll
    for (int ni = 0; ni < 4; ++ni)
      #pragma unroll
      for (int r = 0; r < 4; ++r) {
        int m = m0 + wr * 64 + mi * 16 + ((lane >> 4) << 2) + r;
        int n = n0 + wc * 64 + ni * 16 + (lane & 15);
        out[(size_t)m * D_DIM + n] = acc[mi][ni][r] + bo[n];
      }
}

// ===================== V transpose: [B,H,S,HD] -> [B,H,HD,S] =====================
__global__ __launch_bounds__(256) void transpose_v_kernel(const __bf16* __restrict__ V,
                                                          __bf16* __restrict__ Vt) {
  __shared__ __bf16 tile[64][72];  // pad 72 keeps 16B row alignment, breaks bank aliasing
  int bh = blockIdx.y, s0 = blockIdx.x * 64;
  const __bf16* Vp = V + (size_t)bh * S_LEN * HDIM;
  __bf16* Vtp = Vt + (size_t)bh * HDIM * S_LEN;
  int t = threadIdx.x;
  #pragma unroll
  for (int i = 0; i < 4; ++i) {
    int q = t + i * 256;              // quad index 0..1023
    int row = q >> 4, c4 = (q & 15) * 4;
    b4 v = *reinterpret_cast<const b4*>(&Vp[(size_t)(s0 + row) * HDIM + c4]);
    *reinterpret_cast<b4*>(&tile[row][c4]) = v;
  }
  __syncthreads();
  #pragma unroll
  for (int i = 0; i < 4; ++i) {
    int q = t + i * 256;
    int d = q >> 4, s4 = (q & 15) * 4;
    b4 v;
    v.x = tile[s4 + 0][d]; v.y = tile[s4 + 1][d];
    v.z = tile[s4 + 2][d]; v.w = tile[s4 + 3][d];
    *reinterpret_cast<b4*>(&Vtp[(size_t)d * S_LEN + s0 + s4]) = v;
  }
}

// ===================== flash attention =====================
// grid (S/64, B*H), 256 threads = 4 waves; each wave owns 16 q-rows.
// Q,K: [B,H,S,HD] bf16; Vt: [B,H,HD,S] bf16; ctx out: [B,S,D] bf16.
// 2-phase: double-buffered K/V, prefetch next tile before computing current,
// single barrier per iteration (implicit vmcnt drain lands AFTER compute).
#define NT (S_LEN / 64)
__global__ __launch_bounds__(256) void attn_kernel(const __bf16* __restrict__ Q,
                                                   const __bf16* __restrict__ K,
                                                   const __bf16* __restrict__ Vt,
                                                   __bf16* __restrict__ ctx) {
  __shared__ __bf16 Ks[2][64 * 64];   // [kv][d], swizzled
  __shared__ __bf16 Vs[2][64 * 64];   // [d][kv], swizzled
  __shared__ __bf16 Ps[4][16 * 64];   // per-wave P tile [qi][kv], swizzled
  int t = threadIdx.x, lane = t & 63, w = t >> 6;
  int bh = blockIdx.y, b = bh >> 3, h = bh & 7;
  int qw = blockIdx.x * 64 + w * 16;  // wave's first q row
  const __bf16* Qp = Q + (size_t)bh * S_LEN * HDIM;
  const __bf16* Kp = K + (size_t)bh * S_LEN * HDIM;
  const __bf16* Vp = Vt + (size_t)bh * HDIM * S_LEN;

  // Q fragments in registers for the whole kernel; fold in 1/sqrt(dk)=0.125
  // (power of two -> exact in bf16).
  b8 qf[2];
  #pragma unroll
  for (int kk = 0; kk < 2; ++kk) {
    qf[kk] = *reinterpret_cast<const b8*>(&Qp[(size_t)(qw + (lane & 15)) * HDIM + kk * 32 + ((lane >> 4) << 3)]);
    #pragma unroll
    for (int e = 0; e < 8; ++e) qf[kk][e] = (__bf16)((float)qf[kk][e] * 0.125f);
  }

  const f4 zero = {0.f, 0.f, 0.f, 0.f};
  f4 oacc[4];
  #pragma unroll
  for (int df = 0; df < 4; ++df) oacc[df] = zero;
  float mr[4], lr[4];
  #pragma unroll
  for (int r = 0; r < 4; ++r) { mr[r] = -1e30f; lr[r] = 0.f; }

  auto stage = [&](int kt, int buf) {
    #pragma unroll
    for (int i = 0; i < 2; ++i) {
      int o = i * 4096 + t * 16;
      int row = o >> 7, cb = o & 127;
      int scb = cb ^ ((row & 7) << 4);   // inverse-swizzled source column
      load_lds16((const char*)Kp + (size_t)(kt + row) * 128 + scb, (char*)Ks[buf] + o);
      load_lds16((const char*)Vp + (size_t)row * (S_LEN * 2) + (size_t)kt * 2 + scb, (char*)Vs[buf] + o);
    }
  };

  stage(0, 0);
  __syncthreads();   // implicit vmcnt(0) drain -> buf0 ready
  int cur = 0;

  for (int it = 0; it < NT; ++it) {
    if (it + 1 < NT) stage((it + 1) * 64, cur ^ 1);   // prefetch next tile

    // S = Q K^T (rows=q via C-layout, cols=kv); Q pre-scaled
    f4 sf[4];
    #pragma unroll
    for (int nf = 0; nf < 4; ++nf) {
      sf[nf] = zero;
      #pragma unroll
      for (int kk = 0; kk < 2; ++kk) {
        b8 kf = lds_frag(Ks[cur], nf * 16 + (lane & 15), kk * 64 + ((lane >> 4) << 4));
        sf[nf] = mfma16(qf[kk], kf, sf[nf]);
      }
    }

    // online softmax: row r of this lane's group = (lane>>4)*4 + r
    float alpha[4];
    #pragma unroll
    for (int r = 0; r < 4; ++r) {
      float mx = fmaxf(fmaxf(sf[0][r], sf[1][r]), fmaxf(sf[2][r], sf[3][r]));
      #pragma unroll
      for (int off = 8; off >= 1; off >>= 1) mx = fmaxf(mx, __shfl_xor(mx, off, 16));
      float mn = fmaxf(mr[r], mx);
      alpha[r] = __expf(mr[r] - mn);
      mr[r] = mn;
      lr[r] *= alpha[r];
    }
    // P = exp(S - m), per-lane partial row sums, spill P to LDS (bf16, swizzled)
    #pragma unroll
    for (int nf = 0; nf < 4; ++nf)
      #pragma unroll
      for (int r = 0; r < 4; ++r) {
        float p = __expf(sf[nf][r] - mr[r]);
        lr[r] += p;
        int pr = ((lane >> 4) << 2) + r;
        int pc2 = (nf * 16 + (lane & 15)) * 2;
        *(__bf16*)((char*)&Ps[w][0] + pr * 128 + (pc2 ^ ((pr & 7) << 4))) = (__bf16)p;
      }
    // rescale running context
    #pragma unroll
    for (int df = 0; df < 4; ++df)
      #pragma unroll
      for (int r = 0; r < 4; ++r) oacc[df][r] *= alpha[r];

    // PV: A = P (re-read in A-layout from wave-private LDS; same-wave DS ops ordered)
    #pragma unroll
    for (int df = 0; df < 4; ++df) {
      #pragma unroll
      for (int ks = 0; ks < 2; ++ks) {
        b8 pf = lds_frag(&Ps[w][0], lane & 15, ks * 64 + ((lane >> 4) << 4));
        b8 vf = lds_frag(Vs[cur], df * 16 + (lane & 15), ks * 64 + ((lane >> 4) << 4));
        oacc[df] = mfma16(pf, vf, oacc[df]);
      }
    }

    __syncthreads();  // drain prefetch vmcnt + all waves done reading buf[cur]
    cur ^= 1;
  }

  // finish: reduce row sums across the 16-lane group, normalize, write ctx [B,S,D]
  #pragma unroll
  for (int r = 0; r < 4; ++r)
    #pragma unroll
    for (int off = 8; off >= 1; off >>= 1) lr[r] += __shfl_xor(lr[r], off, 16);

  __bf16* cp = ctx + (size_t)b * S_LEN * D_DIM + (size_t)h * HDIM;
  #pragma unroll
  for (int df = 0; df < 4; ++df)
    #pragma unroll
    for (int r = 0; r < 4; ++r) {
      int q = qw + ((lane >> 4) << 2) + r;
      int d = df * 16 + (lane & 15);
      cp[(size_t)q * D_DIM + d] = (__bf16)(oacc[df][r] / lr[r]);
    }
}

// ===================== launch =====================
extern "C" void kernel_launch(void* const* d_in, const int* in_sizes, int n_in,
                              void* d_out, int out_size, void* d_ws, size_t ws_size,
                              hipStream_t stream) {
  const float* x  = (const float*)d_in[0];
  const float* Wq = (const float*)d_in[1];
  const float* bq = (const float*)d_in[2];
  const float* Wk = (const float*)d_in[3];
  const float* bk = (const float*)d_in[4];
  const float* Wv = (const float*)d_in[5];
  const float* bv = (const float*)d_in[6];
  const float* Wo = (const float*)d_in[7];
  const float* bo = (const float*)d_in[8];
  float* out = (float*)d_out;

  // workspace layout (bf16 elements); ctx reuses the x-bf16 slot (dead after QKV)
  char* ws = (char*)d_ws;
  __bf16* xb   = (__bf16*)(ws);                               // 8192*512
  __bf16* wqb  = xb  + 4194304;                               // 512*512
  __bf16* wkb  = wqb + 262144;
  __bf16* wvb  = wkb + 262144;
  __bf16* wob  = wvb + 262144;
  __bf16* Qb   = wob + 262144;                                // 4*8*2048*64
  __bf16* Kb   = Qb  + 4194304;
  __bf16* Vb   = Kb  + 4194304;
  __bf16* Vtb  = Vb  + 4194304;
  __bf16* ctxb = xb;  // reuse

  cvt_kernel<<<dim3(4096), dim3(256), 0, stream>>>(x, xb);
  cvt_w_kernel<<<dim3(256, 4), dim3(256), 0, stream>>>(Wq, Wk, Wv, Wo, wqb, wkb, wvb, wob);
  gemm_qkv_kernel<<<dim3(64, 4, 3), dim3(256), 0, stream>>>(xb, wqb, wkb, wvb, bq, bk, bv, Qb, Kb, Vb);
  transpose_v_kernel<<<dim3(32, 32), dim3(256), 0, stream>>>(Vb, Vtb);
  attn_kernel<<<dim3(32, 32), dim3(256), 0, stream>>>(Qb, Kb, Vtb, ctxb);
  gemm_o_kernel<<<dim3(64, 4), dim3(256), 0, stream>>>(ctxb, wob, bo, out);
}

// Round 3
// 119.523 us; speedup vs baseline: 1.5428x; 1.2217x over previous
//
#include <hip/hip_runtime.h>
#include <hip/hip_bf16.h>
#include <cstdint>
#include <cstddef>

// Problem dims (fixed): B=4, S=2048, D=512, H=8, HD=64, M = B*S = 8192
#define S_LEN 2048
#define D_DIM 512
#define NHEAD 8
#define HDIM  64

typedef __attribute__((ext_vector_type(8)))  __bf16 b8;    // MFMA A/B fragment (4 VGPRs)
typedef __attribute__((ext_vector_type(4)))  __bf16 b4;    // 8-byte vector
typedef __attribute__((ext_vector_type(4)))  float  f4;    // 16x16 C fragment
typedef __attribute__((ext_vector_type(16))) float  f16v;  // 32x32 C fragment
typedef __attribute__((ext_vector_type(4)))  unsigned int u32x4;

#define AS_GLOBAL __attribute__((address_space(1)))
#define AS_LDS    __attribute__((address_space(3)))

__device__ __forceinline__ void load_lds16(const void* g, void* l) {
  __builtin_amdgcn_global_load_lds((const AS_GLOBAL void*)g, (AS_LDS void*)l, 16, 0, 0);
}

__device__ __forceinline__ f4 mfma16(b8 a, b8 b, f4 c) {
  return __builtin_amdgcn_mfma_f32_16x16x32_bf16(a, b, c, 0, 0, 0);
}
__device__ __forceinline__ f16v mfma32(b8 a, b8 b, f16v c) {
  return __builtin_amdgcn_mfma_f32_32x32x16_bf16(a, b, c, 0, 0, 0);
}

// v_cvt_pk_bf16_f32: D.lo = bf16(S0), D.hi = bf16(S1)
__device__ __forceinline__ unsigned int pkbf(float lo, float hi_) {
  unsigned int r;
  asm("v_cvt_pk_bf16_f32 %0, %1, %2" : "=v"(r) : "v"(lo), "v"(hi_));
  return r;
}

// Swizzled read from an LDS tile with 128-byte rows. Physical byte =
// row*128 + (bytecol ^ ((row&7)<<4)); staging pre-applies the same XOR to the
// global source column so logical data lands in the right slot (involution).
__device__ __forceinline__ b8 lds_frag(const __bf16* base, int row, int bc) {
  return *reinterpret_cast<const b8*>((const char*)base + row * 128 + (bc ^ ((row & 7) << 4)));
}

// ===================== fp32 -> bf16 conversion =====================
__global__ __launch_bounds__(256) void cvt_kernel(const float* __restrict__ in,
                                                  __bf16* __restrict__ out) {
  int i = (blockIdx.x * 256 + threadIdx.x) * 4;
  float4 v = *reinterpret_cast<const float4*>(in + i);
  b4 o;
  o.x = (__bf16)v.x; o.y = (__bf16)v.y; o.z = (__bf16)v.z; o.w = (__bf16)v.w;
  *reinterpret_cast<b4*>(out + i) = o;
}

__global__ __launch_bounds__(256) void cvt_w_kernel(const float* __restrict__ w0, const float* __restrict__ w1,
                                                    const float* __restrict__ w2, const float* __restrict__ w3,
                                                    __bf16* o0, __bf16* o1, __bf16* o2, __bf16* o3) {
  const float* in = blockIdx.y == 0 ? w0 : blockIdx.y == 1 ? w1 : blockIdx.y == 2 ? w2 : w3;
  __bf16* out     = blockIdx.y == 0 ? o0 : blockIdx.y == 1 ? o1 : blockIdx.y == 2 ? o2 : o3;
  int i = (blockIdx.x * 256 + threadIdx.x) * 4;
  float4 v = *reinterpret_cast<const float4*>(in + i);
  b4 o;
  o.x = (__bf16)v.x; o.y = (__bf16)v.y; o.z = (__bf16)v.z; o.w = (__bf16)v.w;
  *reinterpret_cast<b4*>(out + i) = o;
}

// ===================== GEMM core: C(128x128) = A * W^T =====================
__device__ __forceinline__ void gemm_core(const __bf16* __restrict__ A, const __bf16* __restrict__ W,
                                          int m0, int n0, __bf16* As, __bf16* Bs, f4 acc[4][4]) {
  const int t = threadIdx.x;
  const int lane = t & 63;
  const int w = t >> 6, wr = w >> 1, wc = w & 1;
  const f4 zero = {0.f, 0.f, 0.f, 0.f};
  #pragma unroll
  for (int mi = 0; mi < 4; ++mi)
    #pragma unroll
    for (int ni = 0; ni < 4; ++ni) acc[mi][ni] = zero;

  const char* Ab = (const char*)A;
  const char* Wb = (const char*)W;
  for (int kt = 0; kt < 512; kt += 64) {
    __syncthreads();
    #pragma unroll
    for (int i = 0; i < 4; ++i) {
      int o = i * 4096 + t * 16;
      int row = o >> 7, cb = o & 127;
      int scb = cb ^ ((row & 7) << 4);
      load_lds16(Ab + ((size_t)(m0 + row) * 512 + kt) * 2 + scb, (char*)As + o);
      load_lds16(Wb + ((size_t)(n0 + row) * 512 + kt) * 2 + scb, (char*)Bs + o);
    }
    __syncthreads();
    #pragma unroll
    for (int kk = 0; kk < 2; ++kk) {
      b8 af[4], bf[4];
      #pragma unroll
      for (int mi = 0; mi < 4; ++mi)
        af[mi] = lds_frag(As, wr * 64 + mi * 16 + (lane & 15), kk * 64 + ((lane >> 4) << 4));
      #pragma unroll
      for (int ni = 0; ni < 4; ++ni)
        bf[ni] = lds_frag(Bs, wc * 64 + ni * 16 + (lane & 15), kk * 64 + ((lane >> 4) << 4));
      #pragma unroll
      for (int mi = 0; mi < 4; ++mi)
        #pragma unroll
        for (int ni = 0; ni < 4; ++ni)
          acc[mi][ni] = mfma16(af[mi], bf[ni], acc[mi][ni]);
    }
  }
}

// ===================== QKV projection =====================
// z picks {Wq,Wk,Wv}. Writes [B,H,S,HD] bf16. Q is pre-scaled by 1/sqrt(dk)=0.125.
__global__ __launch_bounds__(256) void gemm_qkv_kernel(
    const __bf16* __restrict__ xb,
    const __bf16* __restrict__ wq, const __bf16* __restrict__ wk, const __bf16* __restrict__ wv,
    const float* __restrict__ bq, const float* __restrict__ bk, const float* __restrict__ bv,
    __bf16* Qo, __bf16* Ko, __bf16* Vo) {
  __shared__ __bf16 As[128 * 64];
  __shared__ __bf16 Bs[128 * 64];
  int z = blockIdx.z;
  const __bf16* W = z == 0 ? wq : (z == 1 ? wk : wv);
  const float* bias = z == 0 ? bq : (z == 1 ? bk : bv);
  __bf16* out = z == 0 ? Qo : (z == 1 ? Ko : Vo);
  const float sc = (z == 0) ? 0.125f : 1.0f;
  int m0 = blockIdx.x * 128, n0 = blockIdx.y * 128;
  f4 acc[4][4];
  gemm_core(xb, W, m0, n0, As, Bs, acc);
  int t = threadIdx.x, lane = t & 63, w = t >> 6, wr = w >> 1, wc = w & 1;
  #pragma unroll
  for (int mi = 0; mi < 4; ++mi)
    #pragma unroll
    for (int ni = 0; ni < 4; ++ni)
      #pragma unroll
      for (int r = 0; r < 4; ++r) {
        int m = m0 + wr * 64 + mi * 16 + ((lane >> 4) << 2) + r;
        int n = n0 + wc * 64 + ni * 16 + (lane & 15);
        float v = (acc[mi][ni][r] + bias[n]) * sc;
        int b = m >> 11, s = m & 2047, h = n >> 6, hd = n & 63;
        out[(((size_t)(b * NHEAD + h)) * S_LEN + s) * HDIM + hd] = (__bf16)v;
      }
}

// ===================== output projection =====================
__global__ __launch_bounds__(256) void gemm_o_kernel(const __bf16* __restrict__ ctx,
                                                     const __bf16* __restrict__ wo,
                                                     const float* __restrict__ bo,
                                                     float* __restrict__ out) {
  __shared__ __bf16 As[128 * 64];
  __shared__ __bf16 Bs[128 * 64];
  int m0 = blockIdx.x * 128, n0 = blockIdx.y * 128;
  f4 acc[4][4];
  gemm_core(ctx, wo, m0, n0, As, Bs, acc);
  int t = threadIdx.x, lane = t & 63, w = t >> 6, wr = w >> 1, wc = w & 1;
  #pragma unroll
  for (int mi = 0; mi < 4; ++mi)
    #pragma unroll
    for (int ni = 0; ni < 4; ++ni)
      #pragma unroll
      for (int r = 0; r < 4; ++r) {
        int m = m0 + wr * 64 + mi * 16 + ((lane >> 4) << 2) + r;
        int n = n0 + wc * 64 + ni * 16 + (lane & 15);
        out[(size_t)m * D_DIM + n] = acc[mi][ni][r] + bo[n];
      }
}

// ===================== V transpose: [B,H,S,HD] -> [B,H,HD,S] =====================
__global__ __launch_bounds__(256) void transpose_v_kernel(const __bf16* __restrict__ V,
                                                          __bf16* __restrict__ Vt) {
  __shared__ __bf16 tile[64][72];
  int bh = blockIdx.y, s0 = blockIdx.x * 64;
  const __bf16* Vp = V + (size_t)bh * S_LEN * HDIM;
  __bf16* Vtp = Vt + (size_t)bh * HDIM * S_LEN;
  int t = threadIdx.x;
  #pragma unroll
  for (int i = 0; i < 4; ++i) {
    int q = t + i * 256;
    int row = q >> 4, c4 = (q & 15) * 4;
    b4 v = *reinterpret_cast<const b4*>(&Vp[(size_t)(s0 + row) * HDIM + c4]);
    *reinterpret_cast<b4*>(&tile[row][c4]) = v;
  }
  __syncthreads();
  #pragma unroll
  for (int i = 0; i < 4; ++i) {
    int q = t + i * 256;
    int d = q >> 4, s4 = (q & 15) * 4;
    b4 v;
    v.x = tile[s4 + 0][d]; v.y = tile[s4 + 1][d];
    v.z = tile[s4 + 2][d]; v.w = tile[s4 + 3][d];
    *reinterpret_cast<b4*>(&Vtp[(size_t)d * S_LEN + s0 + s4]) = v;
  }
}

// ===================== flash attention (32x32 swapped-QK^T, in-reg softmax) ===
// grid (S/128, B*H), 256 threads = 4 waves; each wave owns 32 q-rows.
// Swapped QK^T: S^T = mfma(A=K, B=Q) -> each lane owns ONE q column (q=lane&31);
// softmax fully in-register; P->bf16 via cvt_pk + cross-half shfl exchange feeds
// PV's B operand; PV computes O^T = mfma(A=Vt, B=P) so lane keeps owning one q.
#define NT (S_LEN / 64)

// Build PV B-fragment for one k-slot from 8 f32 P-values (C-layout regs
// base..base+7 of tile st). Word w sources lane-half (w>>1), regs
// base + 4*hd + 2*(w&1) where hd = destination half. Exchange across
// halves via shfl_xor(.,32) + select.
#define MKFRAG(dst, st, base) do {                                   \
    unsigned int A0_ = pkbf((st)[(base)+0], (st)[(base)+1]);         \
    unsigned int A1_ = pkbf((st)[(base)+2], (st)[(base)+3]);         \
    unsigned int B0_ = pkbf((st)[(base)+4], (st)[(base)+5]);         \
    unsigned int B1_ = pkbf((st)[(base)+6], (st)[(base)+7]);         \
    unsigned int xA0_ = (unsigned int)__shfl_xor((int)A0_, 32);      \
    unsigned int xA1_ = (unsigned int)__shfl_xor((int)A1_, 32);      \
    unsigned int xB0_ = (unsigned int)__shfl_xor((int)B0_, 32);      \
    unsigned int xB1_ = (unsigned int)__shfl_xor((int)B1_, 32);      \
    u32x4 wv_;                                                       \
    wv_.x = hi ? xB0_ : A0_;                                         \
    wv_.y = hi ? xB1_ : A1_;                                         \
    wv_.z = hi ? B0_ : xA0_;                                         \
    wv_.w = hi ? B1_ : xA1_;                                         \
    dst = __builtin_bit_cast(b8, wv_);                               \
  } while (0)

__global__ __launch_bounds__(256) void attn_kernel(const __bf16* __restrict__ Q,
                                                   const __bf16* __restrict__ K,
                                                   const __bf16* __restrict__ Vt,
                                                   __bf16* __restrict__ ctx) {
  __shared__ __bf16 Ks[2][64 * 64];   // [kv][d], swizzled 128B rows
  __shared__ __bf16 Vs[2][64 * 64];   // [d][kv], swizzled 128B rows
  int t = threadIdx.x, lane = t & 63, w = t >> 6;
  int lane31 = lane & 31, hi = lane >> 5;
  int bh = blockIdx.y, b = bh >> 3, h = bh & 7;
  int qw = blockIdx.x * 128 + w * 32;       // wave's first q row
  int q = qw + lane31;                      // this lane's q row
  const __bf16* Qp = Q + (size_t)bh * S_LEN * HDIM;
  const __bf16* Kp = K + (size_t)bh * S_LEN * HDIM;
  const __bf16* Vp = Vt + (size_t)bh * HDIM * S_LEN;

  // Q fragments (B-operand: col=q=lane31, k=d=ks*16+hi*8+e). Q pre-scaled.
  b8 qf[4];
  #pragma unroll
  for (int ks = 0; ks < 4; ++ks)
    qf[ks] = *reinterpret_cast<const b8*>(&Qp[(size_t)q * HDIM + ks * 16 + hi * 8]);

  const f16v Z16 = {0,0,0,0,0,0,0,0,0,0,0,0,0,0,0,0};
  f16v o0 = Z16, o1 = Z16;   // O^T accum: rows d (0-31 / 32-63), col q
  float mr = -1e30f, lsum = 0.f;

  auto stage = [&](int kt, int buf) {
    #pragma unroll
    for (int i = 0; i < 2; ++i) {
      int o = i * 4096 + t * 16;
      int row = o >> 7, cb = o & 127;
      int scb = cb ^ ((row & 7) << 4);
      load_lds16((const char*)Kp + (size_t)(kt + row) * 128 + scb, (char*)Ks[buf] + o);
      load_lds16((const char*)Vp + (size_t)row * (S_LEN * 2) + (size_t)kt * 2 + scb, (char*)Vs[buf] + o);
    }
  };

  stage(0, 0);
  __syncthreads();
  int cur = 0;

  for (int it = 0; it < NT; ++it) {
    if (it + 1 < NT) stage((it + 1) * 64, cur ^ 1);

    // S^T = K * Q^T: tiles t0 (kv 0-31), t1 (kv 32-63); each lane: col q, rows kv
    f16v t0 = Z16, t1 = Z16;
    #pragma unroll
    for (int ks = 0; ks < 4; ++ks) {               // d-slots of 16
      b8 kf0 = lds_frag(Ks[cur], lane31,      hi * 16 + ks * 32);
      b8 kf1 = lds_frag(Ks[cur], 32 + lane31, hi * 16 + ks * 32);
      t0 = mfma32(kf0, qf[ks], t0);
      t1 = mfma32(kf1, qf[ks], t1);
    }

    // row max over 64 kv: 31 in-lane fmax + 1 cross-half exchange
    float mx = t0[0];
    #pragma unroll
    for (int r = 1; r < 16; ++r) mx = fmaxf(mx, t0[r]);
    #pragma unroll
    for (int r = 0; r < 16; ++r) mx = fmaxf(mx, t1[r]);
    mx = fmaxf(mx, __shfl_xor(mx, 32));

    // defer-max: only rescale when max grew by > THR (P bounded by e^8)
    if (!__all(mx - mr <= 8.0f)) {
      float mn = fmaxf(mr, mx);
      float alpha = __expf(mr - mn);
      mr = mn;
      lsum *= alpha;
      o0 *= alpha;
      o1 *= alpha;
    }

    // P = exp(S - m) in place; per-lane partial row sum
    #pragma unroll
    for (int r = 0; r < 16; ++r) { t0[r] = __expf(t0[r] - mr); lsum += t0[r]; }
    #pragma unroll
    for (int r = 0; r < 16; ++r) { t1[r] = __expf(t1[r] - mr); lsum += t1[r]; }

    // pack P to bf16 PV B-fragments (k-slots ks=0..3 over kv)
    b8 pa[4];
    MKFRAG(pa[0], t0, 0);
    MKFRAG(pa[1], t0, 8);
    MKFRAG(pa[2], t1, 0);
    MKFRAG(pa[3], t1, 8);

    // O^T += V^T * P^T
    #pragma unroll
    for (int ks = 0; ks < 4; ++ks) {
      b8 vf0 = lds_frag(Vs[cur], lane31,      hi * 16 + ks * 32);
      b8 vf1 = lds_frag(Vs[cur], 32 + lane31, hi * 16 + ks * 32);
      o0 = mfma32(vf0, pa[ks], o0);
      o1 = mfma32(vf1, pa[ks], o1);
    }

    __syncthreads();  // drain prefetch vmcnt + all waves done reading buf[cur]
    cur ^= 1;
  }

  // combine the two kv-halves' partial sums; normalize; write ctx [B,S,D]
  float l = lsum + __shfl_xor(lsum, 32);
  float inv = 1.0f / l;
  __bf16* cp = ctx + (size_t)b * S_LEN * D_DIM + (size_t)q * D_DIM + (size_t)h * HDIM;
  #pragma unroll
  for (int g = 0; g < 4; ++g) {
    b4 v0, v1;
    #pragma unroll
    for (int j = 0; j < 4; ++j) {
      v0[j] = (__bf16)(o0[4 * g + j] * inv);
      v1[j] = (__bf16)(o1[4 * g + j] * inv);
    }
    int d0 = 8 * g + 4 * hi;          // d = (r&3) + 8*(r>>2) + 4*hi
    *reinterpret_cast<b4*>(cp + d0)      = v0;
    *reinterpret_cast<b4*>(cp + 32 + d0) = v1;
  }
}

// ===================== launch =====================
extern "C" void kernel_launch(void* const* d_in, const int* in_sizes, int n_in,
                              void* d_out, int out_size, void* d_ws, size_t ws_size,
                              hipStream_t stream) {
  const float* x  = (const float*)d_in[0];
  const float* Wq = (const float*)d_in[1];
  const float* bq = (const float*)d_in[2];
  const float* Wk = (const float*)d_in[3];
  const float* bk = (const float*)d_in[4];
  const float* Wv = (const float*)d_in[5];
  const float* bv = (const float*)d_in[6];
  const float* Wo = (const float*)d_in[7];
  const float* bo = (const float*)d_in[8];
  float* out = (float*)d_out;

  char* ws = (char*)d_ws;
  __bf16* xb   = (__bf16*)(ws);                               // 8192*512
  __bf16* wqb  = xb  + 4194304;                               // 512*512
  __bf16* wkb  = wqb + 262144;
  __bf16* wvb  = wkb + 262144;
  __bf16* wob  = wvb + 262144;
  __bf16* Qb   = wob + 262144;                                // 4*8*2048*64
  __bf16* Kb   = Qb  + 4194304;
  __bf16* Vb   = Kb  + 4194304;
  __bf16* Vtb  = Vb  + 4194304;
  __bf16* ctxb = xb;  // reuse (x dead after QKV)

  cvt_kernel<<<dim3(4096), dim3(256), 0, stream>>>(x, xb);
  cvt_w_kernel<<<dim3(256, 4), dim3(256), 0, stream>>>(Wq, Wk, Wv, Wo, wqb, wkb, wvb, wob);
  gemm_qkv_kernel<<<dim3(64, 4, 3), dim3(256), 0, stream>>>(xb, wqb, wkb, wvb, bq, bk, bv, Qb, Kb, Vb);
  transpose_v_kernel<<<dim3(32, 32), dim3(256), 0, stream>>>(Vb, Vtb);
  attn_kernel<<<dim3(16, 32), dim3(256), 0, stream>>>(Qb, Kb, Vtb, ctxb);
  gemm_o_kernel<<<dim3(64, 4), dim3(256), 0, stream>>>(ctxb, wob, bo, out);
}

// Round 5
// 116.307 us; speedup vs baseline: 1.5855x; 1.0276x over previous
//
#include <hip/hip_runtime.h>
#include <hip/hip_bf16.h>
#include <cstdint>
#include <cstddef>

// Problem dims (fixed): B=4, S=2048, D=512, H=8, HD=64, M = B*S = 8192
#define S_LEN 2048
#define D_DIM 512
#define NHEAD 8
#define HDIM  64

typedef __attribute__((ext_vector_type(8)))  __bf16 b8;    // MFMA A/B fragment (4 VGPRs)
typedef __attribute__((ext_vector_type(4)))  __bf16 b4;    // 8-byte vector
typedef __attribute__((ext_vector_type(4)))  float  f4;    // 16x16 C fragment
typedef __attribute__((ext_vector_type(16))) float  f16v;  // 32x32 C fragment
typedef __attribute__((ext_vector_type(4)))  unsigned int u32x4;

#define AS_GLOBAL __attribute__((address_space(1)))
#define AS_LDS    __attribute__((address_space(3)))

__device__ __forceinline__ void load_lds16(const void* g, void* l) {
  __builtin_amdgcn_global_load_lds((const AS_GLOBAL void*)g, (AS_LDS void*)l, 16, 0, 0);
}

__device__ __forceinline__ f4 mfma16(b8 a, b8 b, f4 c) {
  return __builtin_amdgcn_mfma_f32_16x16x32_bf16(a, b, c, 0, 0, 0);
}
__device__ __forceinline__ f16v mfma32(b8 a, b8 b, f16v c) {
  return __builtin_amdgcn_mfma_f32_32x32x16_bf16(a, b, c, 0, 0, 0);
}

// v_cvt_pk_bf16_f32: D.lo = bf16(S0), D.hi = bf16(S1)
__device__ __forceinline__ unsigned int pkbf(float lo, float hi_) {
  unsigned int r;
  asm("v_cvt_pk_bf16_f32 %0, %1, %2" : "=v"(r) : "v"(lo), "v"(hi_));
  return r;
}

// Swizzled read from an LDS tile with 128-byte rows. Physical byte =
// row*128 + (bytecol ^ ((row&7)<<4)); staging pre-applies the same XOR to the
// global source column so logical data lands in the right slot (involution).
__device__ __forceinline__ b8 lds_frag(const __bf16* base, int row, int bc) {
  return *reinterpret_cast<const b8*>((const char*)base + row * 128 + (bc ^ ((row & 7) << 4)));
}

// ===================== fp32 -> bf16 conversion =====================
__global__ __launch_bounds__(256) void cvt_kernel(const float* __restrict__ in,
                                                  __bf16* __restrict__ out) {
  int i = (blockIdx.x * 256 + threadIdx.x) * 4;
  float4 v = *reinterpret_cast<const float4*>(in + i);
  b4 o;
  o.x = (__bf16)v.x; o.y = (__bf16)v.y; o.z = (__bf16)v.z; o.w = (__bf16)v.w;
  *reinterpret_cast<b4*>(out + i) = o;
}

__global__ __launch_bounds__(256) void cvt_w_kernel(const float* __restrict__ w0, const float* __restrict__ w1,
                                                    const float* __restrict__ w2, const float* __restrict__ w3,
                                                    __bf16* o0, __bf16* o1, __bf16* o2, __bf16* o3) {
  const float* in = blockIdx.y == 0 ? w0 : blockIdx.y == 1 ? w1 : blockIdx.y == 2 ? w2 : w3;
  __bf16* out     = blockIdx.y == 0 ? o0 : blockIdx.y == 1 ? o1 : blockIdx.y == 2 ? o2 : o3;
  int i = (blockIdx.x * 256 + threadIdx.x) * 4;
  float4 v = *reinterpret_cast<const float4*>(in + i);
  b4 o;
  o.x = (__bf16)v.x; o.y = (__bf16)v.y; o.z = (__bf16)v.z; o.w = (__bf16)v.w;
  *reinterpret_cast<b4*>(out + i) = o;
}

// ===================== GEMM core: C(128x128) = A * W^T =====================
__device__ __forceinline__ void gemm_core(const __bf16* __restrict__ A, const __bf16* __restrict__ W,
                                          int m0, int n0, __bf16* As, __bf16* Bs, f4 acc[4][4]) {
  const int t = threadIdx.x;
  const int lane = t & 63;
  const int w = t >> 6, wr = w >> 1, wc = w & 1;
  const f4 zero = {0.f, 0.f, 0.f, 0.f};
  #pragma unroll
  for (int mi = 0; mi < 4; ++mi)
    #pragma unroll
    for (int ni = 0; ni < 4; ++ni) acc[mi][ni] = zero;

  const char* Ab = (const char*)A;
  const char* Wb = (const char*)W;
  for (int kt = 0; kt < 512; kt += 64) {
    __syncthreads();
    #pragma unroll
    for (int i = 0; i < 4; ++i) {
      int o = i * 4096 + t * 16;
      int row = o >> 7, cb = o & 127;
      int scb = cb ^ ((row & 7) << 4);
      load_lds16(Ab + ((size_t)(m0 + row) * 512 + kt) * 2 + scb, (char*)As + o);
      load_lds16(Wb + ((size_t)(n0 + row) * 512 + kt) * 2 + scb, (char*)Bs + o);
    }
    __syncthreads();
    #pragma unroll
    for (int kk = 0; kk < 2; ++kk) {
      b8 af[4], bf[4];
      #pragma unroll
      for (int mi = 0; mi < 4; ++mi)
        af[mi] = lds_frag(As, wr * 64 + mi * 16 + (lane & 15), kk * 64 + ((lane >> 4) << 4));
      #pragma unroll
      for (int ni = 0; ni < 4; ++ni)
        bf[ni] = lds_frag(Bs, wc * 64 + ni * 16 + (lane & 15), kk * 64 + ((lane >> 4) << 4));
      #pragma unroll
      for (int mi = 0; mi < 4; ++mi)
        #pragma unroll
        for (int ni = 0; ni < 4; ++ni)
          acc[mi][ni] = mfma16(af[mi], bf[ni], acc[mi][ni]);
    }
  }
}

// ===================== QKV projection =====================
// z picks {Wq,Wk,Wv}. Writes [B,H,S,HD] bf16.
// Q pre-scaled by (1/sqrt(dk))*log2(e) so attention exp runs in base-2 domain.
__global__ __launch_bounds__(256) void gemm_qkv_kernel(
    const __bf16* __restrict__ xb,
    const __bf16* __restrict__ wq, const __bf16* __restrict__ wk, const __bf16* __restrict__ wv,
    const float* __restrict__ bq, const float* __restrict__ bk, const float* __restrict__ bv,
    __bf16* Qo, __bf16* Ko, __bf16* Vo) {
  __shared__ __bf16 As[128 * 64];
  __shared__ __bf16 Bs[128 * 64];
  int z = blockIdx.z;
  const __bf16* W = z == 0 ? wq : (z == 1 ? wk : wv);
  const float* bias = z == 0 ? bq : (z == 1 ? bk : bv);
  __bf16* out = z == 0 ? Qo : (z == 1 ? Ko : Vo);
  const float sc = (z == 0) ? 0.18033688011112042f : 1.0f;  // 0.125 * log2(e)
  int m0 = blockIdx.x * 128, n0 = blockIdx.y * 128;
  f4 acc[4][4];
  gemm_core(xb, W, m0, n0, As, Bs, acc);
  int t = threadIdx.x, lane = t & 63, w = t >> 6, wr = w >> 1, wc = w & 1;
  #pragma unroll
  for (int mi = 0; mi < 4; ++mi)
    #pragma unroll
    for (int ni = 0; ni < 4; ++ni)
      #pragma unroll
      for (int r = 0; r < 4; ++r) {
        int m = m0 + wr * 64 + mi * 16 + ((lane >> 4) << 2) + r;
        int n = n0 + wc * 64 + ni * 16 + (lane & 15);
        float v = (acc[mi][ni][r] + bias[n]) * sc;
        int b = m >> 11, s = m & 2047, h = n >> 6, hd = n & 63;
        out[(((size_t)(b * NHEAD + h)) * S_LEN + s) * HDIM + hd] = (__bf16)v;
      }
}

// ===================== output projection =====================
__global__ __launch_bounds__(256) void gemm_o_kernel(const __bf16* __restrict__ ctx,
                                                     const __bf16* __restrict__ wo,
                                                     const float* __restrict__ bo,
                                                     float* __restrict__ out) {
  __shared__ __bf16 As[128 * 64];
  __shared__ __bf16 Bs[128 * 64];
  int m0 = blockIdx.x * 128, n0 = blockIdx.y * 128;
  f4 acc[4][4];
  gemm_core(ctx, wo, m0, n0, As, Bs, acc);
  int t = threadIdx.x, lane = t & 63, w = t >> 6, wr = w >> 1, wc = w & 1;
  #pragma unroll
  for (int mi = 0; mi < 4; ++mi)
    #pragma unroll
    for (int ni = 0; ni < 4; ++ni)
      #pragma unroll
      for (int r = 0; r < 4; ++r) {
        int m = m0 + wr * 64 + mi * 16 + ((lane >> 4) << 2) + r;
        int n = n0 + wc * 64 + ni * 16 + (lane & 15);
        out[(size_t)m * D_DIM + n] = acc[mi][ni][r] + bo[n];
      }
}

// ===================== V transpose: [B,H,S,HD] -> [B,H,HD,S] =====================
__global__ __launch_bounds__(256) void transpose_v_kernel(const __bf16* __restrict__ V,
                                                          __bf16* __restrict__ Vt) {
  __shared__ __bf16 tile[64][72];
  int bh = blockIdx.y, s0 = blockIdx.x * 64;
  const __bf16* Vp = V + (size_t)bh * S_LEN * HDIM;
  __bf16* Vtp = Vt + (size_t)bh * HDIM * S_LEN;
  int t = threadIdx.x;
  #pragma unroll
  for (int i = 0; i < 4; ++i) {
    int q = t + i * 256;
    int row = q >> 4, c4 = (q & 15) * 4;
    b4 v = *reinterpret_cast<const b4*>(&Vp[(size_t)(s0 + row) * HDIM + c4]);
    *reinterpret_cast<b4*>(&tile[row][c4]) = v;
  }
  __syncthreads();
  #pragma unroll
  for (int i = 0; i < 4; ++i) {
    int q = t + i * 256;
    int d = q >> 4, s4 = (q & 15) * 4;
    b4 v;
    v.x = tile[s4 + 0][d]; v.y = tile[s4 + 1][d];
    v.z = tile[s4 + 2][d]; v.w = tile[s4 + 3][d];
    *reinterpret_cast<b4*>(&Vtp[(size_t)d * S_LEN + s0 + s4]) = v;
  }
}

// ===================== flash attention (kv-split-2, 8 waves) =====================
// grid (S/128, B*H), 512 threads = 8 waves: 4 q-subtiles (qs=w&3, 32 q each)
// x 2 kv-halves (grp=w>>2, 1024 kv each with private double-buffered K/V LDS).
// Swapped QK^T (A=K, B=Q) -> lane owns one q column; softmax fully in-register;
// P->bf16 via v_cvt_pk_bf16_f32 + v_permlane32_swap_b32 (no LDS round-trip).
// Epilogue merges the two kv-halves' (m, l, O) through LDS (reuses staging).
#define NTG 16  // kv tiles per group: 1024 / 64

// Build PV B-fragment for one 16-k slot from C-layout f32 P regs base..base+7.
// v_permlane32_swap_b32 semantics: vdst.lanes[32:63] <-> vsrc.lanes[0:31]
// (m214-verified call order: A-word is vdst). swap(A0,B0) gives:
//   lo lane: A0 = A0_own,        B0 = A0 from hi partner
//   hi lane: A0 = B0 from lo,    B0 = B0_own
// -> fragment words [A0, A1, B0, B1] for both halves.
#define MKFRAG(dst, st, base) do {                                   \
    unsigned int A0_ = pkbf((st)[(base)+0], (st)[(base)+1]);         \
    unsigned int A1_ = pkbf((st)[(base)+2], (st)[(base)+3]);         \
    unsigned int B0_ = pkbf((st)[(base)+4], (st)[(base)+5]);         \
    unsigned int B1_ = pkbf((st)[(base)+6], (st)[(base)+7]);         \
    asm("v_permlane32_swap_b32 %0, %1" : "+v"(A0_), "+v"(B0_));      \
    asm("v_permlane32_swap_b32 %0, %1" : "+v"(A1_), "+v"(B1_));      \
    u32x4 wv_; wv_.x = A0_; wv_.y = A1_; wv_.z = B0_; wv_.w = B1_;   \
    dst = __builtin_bit_cast(b8, wv_);                               \
  } while (0)

__global__ __launch_bounds__(512, 4) void attn_kernel(const __bf16* __restrict__ Q,
                                                      const __bf16* __restrict__ K,
                                                      const __bf16* __restrict__ Vt,
                                                      __bf16* __restrict__ ctx) {
  __shared__ __bf16 Ks[2][2][64 * 64];   // [grp][buf][kv][d], swizzled 128B rows
  __shared__ __bf16 Vs[2][2][64 * 64];   // [grp][buf][d][kv], swizzled 128B rows
  int t = threadIdx.x, lane = t & 63, w = t >> 6;
  int lane31 = lane & 31, hi = lane >> 5;
  int grp = w >> 2, qs = w & 3, t256 = t & 255;
  int bh = blockIdx.y, b = bh >> 3, h = bh & 7;
  int q = blockIdx.x * 128 + qs * 32 + lane31;   // this lane's q row
  const __bf16* Qp = Q + (size_t)bh * S_LEN * HDIM;
  const __bf16* Kp = K + (size_t)bh * S_LEN * HDIM;
  const __bf16* Vp = Vt + (size_t)bh * HDIM * S_LEN;
  const int kv0 = grp * (S_LEN / 2);

  // Q fragments (B-operand: col=q=lane31, k=d=ks*16+hi*8+e). Q pre-scaled.
  b8 qf[4];
  #pragma unroll
  for (int ks = 0; ks < 4; ++ks)
    qf[ks] = *reinterpret_cast<const b8*>(&Qp[(size_t)q * HDIM + ks * 16 + hi * 8]);

  const f16v Z16 = {0,0,0,0,0,0,0,0,0,0,0,0,0,0,0,0};
  f16v o0 = Z16, o1 = Z16;   // O^T accum: rows d (0-31 / 32-63), col q
  float mr = -1e30f, lsum = 0.f;

  auto stage = [&](int kt, int buf) {
    #pragma unroll
    for (int i = 0; i < 2; ++i) {
      int o = i * 4096 + t256 * 16;
      int row = o >> 7, cb = o & 127;
      int scb = cb ^ ((row & 7) << 4);
      load_lds16((const char*)Kp + (size_t)(kt + row) * 128 + scb, (char*)Ks[grp][buf] + o);
      load_lds16((const char*)Vp + (size_t)row * (S_LEN * 2) + (size_t)kt * 2 + scb, (char*)Vs[grp][buf] + o);
    }
  };

  stage(kv0, 0);
  __syncthreads();
  int cur = 0;

  for (int it = 0; it < NTG; ++it) {
    if (it + 1 < NTG) stage(kv0 + (it + 1) * 64, cur ^ 1);

    // S^T = K * Q^T: t0 (kv+0..31), t1 (kv+32..63); lane: col q, rows kv
    f16v t0 = Z16, t1 = Z16;
    #pragma unroll
    for (int ks = 0; ks < 4; ++ks) {
      b8 kf0 = lds_frag(Ks[grp][cur], lane31,      hi * 16 + ks * 32);
      b8 kf1 = lds_frag(Ks[grp][cur], 32 + lane31, hi * 16 + ks * 32);
      t0 = mfma32(kf0, qf[ks], t0);
      t1 = mfma32(kf1, qf[ks], t1);
    }

    // tree row-max over 64 kv (depth 5 + cross-half exchange)
    float v[16];
    #pragma unroll
    for (int r = 0; r < 16; ++r) v[r] = fmaxf(t0[r], t1[r]);
    #pragma unroll
    for (int s = 8; s >= 1; s >>= 1)
      #pragma unroll
      for (int r = 0; r < 8; ++r)
        if (r < s) v[r] = fmaxf(v[r], v[r + s]);
    float mx = fmaxf(v[0], __shfl_xor(v[0], 32));

    // defer-max (base-2 domain): rescale only when max grew by > 11.5 (~8 nats)
    if (!__all(mx - mr <= 11.5f)) {
      float mn = fmaxf(mr, mx);
      float al = exp2f(mr - mn);
      mr = mn;
      lsum *= al;
      o0 *= al;
      o1 *= al;
    }

    // P = 2^(S2 - m2) in place; per-lane partial row sum
    #pragma unroll
    for (int r = 0; r < 16; ++r) { t0[r] = exp2f(t0[r] - mr); lsum += t0[r]; }
    #pragma unroll
    for (int r = 0; r < 16; ++r) { t1[r] = exp2f(t1[r] - mr); lsum += t1[r]; }

    // pack P to bf16 PV B-fragments (k-slots over kv)
    b8 pa[4];
    MKFRAG(pa[0], t0, 0);
    MKFRAG(pa[1], t0, 8);
    MKFRAG(pa[2], t1, 0);
    MKFRAG(pa[3], t1, 8);

    // O^T += V^T * P^T
    #pragma unroll
    for (int ks = 0; ks < 4; ++ks) {
      b8 vf0 = lds_frag(Vs[grp][cur], lane31,      hi * 16 + ks * 32);
      b8 vf1 = lds_frag(Vs[grp][cur], 32 + lane31, hi * 16 + ks * 32);
      o0 = mfma32(vf0, pa[ks], o0);
      o1 = mfma32(vf1, pa[ks], o1);
    }

    __syncthreads();  // drain prefetch vmcnt + all waves done reading buf[cur]
    cur ^= 1;
  }

  // ---- merge the two kv-halves (grp1 -> LDS -> grp0), then write ctx ----
  float l_own = lsum + __shfl_xor(lsum, 32);
  float* OL = (float*)&Ks[0][0][0];   // [4 qs][64 d][32 q] f32 = 32 KiB (staging dead)
  float* ML = OL + 8192;              // m[4][32] then l[4][32]
  if (grp == 1) {
    #pragma unroll
    for (int g = 0; g < 4; ++g)
      #pragma unroll
      for (int j = 0; j < 4; ++j) {
        int d = 8 * g + 4 * hi + j;
        OL[(qs * 64 + d) * 32 + lane31]      = o0[4 * g + j];
        OL[(qs * 64 + 32 + d) * 32 + lane31] = o1[4 * g + j];
      }
    if (hi == 0) { ML[qs * 32 + lane31] = mr; ML[128 + qs * 32 + lane31] = l_own; }
  }
  __syncthreads();
  if (grp == 0) {
    float m1 = ML[qs * 32 + lane31], l1 = ML[128 + qs * 32 + lane31];
    float mm = fmaxf(mr, m1);
    float s0 = exp2f(mr - mm), s1 = exp2f(m1 - mm);
    float inv = 1.0f / (l_own * s0 + l1 * s1);
    __bf16* cp = ctx + (size_t)b * S_LEN * D_DIM + (size_t)q * D_DIM + (size_t)h * HDIM;
    #pragma unroll
    for (int g = 0; g < 4; ++g) {
      b4 v0, v1;
      #pragma unroll
      for (int j = 0; j < 4; ++j) {
        int d = 8 * g + 4 * hi + j;
        v0[j] = (__bf16)((o0[4 * g + j] * s0 + OL[(qs * 64 + d) * 32 + lane31] * s1) * inv);
        v1[j] = (__bf16)((o1[4 * g + j] * s0 + OL[(qs * 64 + 32 + d) * 32 + lane31] * s1) * inv);
      }
      int d0 = 8 * g + 4 * hi;
      *reinterpret_cast<b4*>(cp + d0)      = v0;
      *reinterpret_cast<b4*>(cp + 32 + d0) = v1;
    }
  }
}

// ===================== launch =====================
extern "C" void kernel_launch(void* const* d_in, const int* in_sizes, int n_in,
                              void* d_out, int out_size, void* d_ws, size_t ws_size,
                              hipStream_t stream) {
  const float* x  = (const float*)d_in[0];
  const float* Wq = (const float*)d_in[1];
  const float* bq = (const float*)d_in[2];
  const float* Wk = (const float*)d_in[3];
  const float* bk = (const float*)d_in[4];
  const float* Wv = (const float*)d_in[5];
  const float* bv = (const float*)d_in[6];
  const float* Wo = (const float*)d_in[7];
  const float* bo = (const float*)d_in[8];
  float* out = (float*)d_out;

  char* ws = (char*)d_ws;
  __bf16* xb   = (__bf16*)(ws);                               // 8192*512
  __bf16* wqb  = xb  + 4194304;                               // 512*512
  __bf16* wkb  = wqb + 262144;
  __bf16* wvb  = wkb + 262144;
  __bf16* wob  = wvb + 262144;
  __bf16* Qb   = wob + 262144;                                // 4*8*2048*64
  __bf16* Kb   = Qb  + 4194304;
  __bf16* Vb   = Kb  + 4194304;
  __bf16* Vtb  = Vb  + 4194304;
  __bf16* ctxb = xb;  // reuse (x dead after QKV)

  cvt_kernel<<<dim3(4096), dim3(256), 0, stream>>>(x, xb);
  cvt_w_kernel<<<dim3(256, 4), dim3(256), 0, stream>>>(Wq, Wk, Wv, Wo, wqb, wkb, wvb, wob);
  gemm_qkv_kernel<<<dim3(64, 4, 3), dim3(256), 0, stream>>>(xb, wqb, wkb, wvb, bq, bk, bv, Qb, Kb, Vb);
  transpose_v_kernel<<<dim3(32, 32), dim3(256), 0, stream>>>(Vb, Vtb);
  attn_kernel<<<dim3(16, 32), dim3(512), 0, stream>>>(Qb, Kb, Vtb, ctxb);
  gemm_o_kernel<<<dim3(64, 4), dim3(256), 0, stream>>>(ctxb, wob, bo, out);
}

// Round 6
// 108.234 us; speedup vs baseline: 1.7037x; 1.0746x over previous
//
#include <hip/hip_runtime.h>
#include <hip/hip_bf16.h>
#include <cstdint>
#include <cstddef>

// Problem dims (fixed): B=4, S=2048, D=512, H=8, HD=64, M = B*S = 8192
#define S_LEN 2048
#define D_DIM 512
#define NHEAD 8
#define HDIM  64

typedef __attribute__((ext_vector_type(8)))  __bf16 b8;    // MFMA A/B fragment (4 VGPRs)
typedef __attribute__((ext_vector_type(4)))  __bf16 b4;    // 8-byte vector
typedef __attribute__((ext_vector_type(4)))  float  f4;    // 16x16 C fragment
typedef __attribute__((ext_vector_type(16))) float  f16v;  // 32x32 C fragment
typedef __attribute__((ext_vector_type(4)))  unsigned int u32x4;

#define AS_GLOBAL __attribute__((address_space(1)))
#define AS_LDS    __attribute__((address_space(3)))

__device__ __forceinline__ void load_lds16(const void* g, void* l) {
  __builtin_amdgcn_global_load_lds((const AS_GLOBAL void*)g, (AS_LDS void*)l, 16, 0, 0);
}

__device__ __forceinline__ f4 mfma16(b8 a, b8 b, f4 c) {
  return __builtin_amdgcn_mfma_f32_16x16x32_bf16(a, b, c, 0, 0, 0);
}
__device__ __forceinline__ f16v mfma32(b8 a, b8 b, f16v c) {
  return __builtin_amdgcn_mfma_f32_32x32x16_bf16(a, b, c, 0, 0, 0);
}

// single-instruction 2^x
__device__ __forceinline__ float exp2v(float x) {
#if __has_builtin(__builtin_amdgcn_exp2f)
  return __builtin_amdgcn_exp2f(x);
#else
  float r; asm("v_exp_f32 %0, %1" : "=v"(r) : "v"(x)); return r;
#endif
}

// v_cvt_pk_bf16_f32: D.lo = bf16(S0), D.hi = bf16(S1)
__device__ __forceinline__ unsigned int pkbf(float lo, float hi_) {
  unsigned int r;
  asm("v_cvt_pk_bf16_f32 %0, %1, %2" : "=v"(r) : "v"(lo), "v"(hi_));
  return r;
}

// Swizzled read from an LDS tile with 128-byte rows. Physical byte =
// row*128 + (bytecol ^ ((row&7)<<4)); staging pre-applies the same XOR to the
// global source column so logical data lands in the right slot (involution).
__device__ __forceinline__ b8 lds_frag(const __bf16* base, int row, int bc) {
  return *reinterpret_cast<const b8*>((const char*)base + row * 128 + (bc ^ ((row & 7) << 4)));
}

// ===================== fp32 -> bf16 conversion =====================
__global__ __launch_bounds__(256) void cvt_kernel(const float* __restrict__ in,
                                                  __bf16* __restrict__ out) {
  int i = (blockIdx.x * 256 + threadIdx.x) * 4;
  float4 v = *reinterpret_cast<const float4*>(in + i);
  b4 o;
  o.x = (__bf16)v.x; o.y = (__bf16)v.y; o.z = (__bf16)v.z; o.w = (__bf16)v.w;
  *reinterpret_cast<b4*>(out + i) = o;
}

__global__ __launch_bounds__(256) void cvt_w_kernel(const float* __restrict__ w0, const float* __restrict__ w1,
                                                    const float* __restrict__ w2, const float* __restrict__ w3,
                                                    __bf16* o0, __bf16* o1, __bf16* o2, __bf16* o3) {
  const float* in = blockIdx.y == 0 ? w0 : blockIdx.y == 1 ? w1 : blockIdx.y == 2 ? w2 : w3;
  __bf16* out     = blockIdx.y == 0 ? o0 : blockIdx.y == 1 ? o1 : blockIdx.y == 2 ? o2 : o3;
  int i = (blockIdx.x * 256 + threadIdx.x) * 4;
  float4 v = *reinterpret_cast<const float4*>(in + i);
  b4 o;
  o.x = (__bf16)v.x; o.y = (__bf16)v.y; o.z = (__bf16)v.z; o.w = (__bf16)v.w;
  *reinterpret_cast<b4*>(out + i) = o;
}

// ===================== GEMM core: C(128x128) = A * W^T =====================
__device__ __forceinline__ void gemm_core(const __bf16* __restrict__ A, const __bf16* __restrict__ W,
                                          int m0, int n0, __bf16* As, __bf16* Bs, f4 acc[4][4]) {
  const int t = threadIdx.x;
  const int lane = t & 63;
  const int w = t >> 6, wr = w >> 1, wc = w & 1;
  const f4 zero = {0.f, 0.f, 0.f, 0.f};
  #pragma unroll
  for (int mi = 0; mi < 4; ++mi)
    #pragma unroll
    for (int ni = 0; ni < 4; ++ni) acc[mi][ni] = zero;

  const char* Ab = (const char*)A;
  const char* Wb = (const char*)W;
  for (int kt = 0; kt < 512; kt += 64) {
    __syncthreads();
    #pragma unroll
    for (int i = 0; i < 4; ++i) {
      int o = i * 4096 + t * 16;
      int row = o >> 7, cb = o & 127;
      int scb = cb ^ ((row & 7) << 4);
      load_lds16(Ab + ((size_t)(m0 + row) * 512 + kt) * 2 + scb, (char*)As + o);
      load_lds16(Wb + ((size_t)(n0 + row) * 512 + kt) * 2 + scb, (char*)Bs + o);
    }
    __syncthreads();
    #pragma unroll
    for (int kk = 0; kk < 2; ++kk) {
      b8 af[4], bf[4];
      #pragma unroll
      for (int mi = 0; mi < 4; ++mi)
        af[mi] = lds_frag(As, wr * 64 + mi * 16 + (lane & 15), kk * 64 + ((lane >> 4) << 4));
      #pragma unroll
      for (int ni = 0; ni < 4; ++ni)
        bf[ni] = lds_frag(Bs, wc * 64 + ni * 16 + (lane & 15), kk * 64 + ((lane >> 4) << 4));
      #pragma unroll
      for (int mi = 0; mi < 4; ++mi)
        #pragma unroll
        for (int ni = 0; ni < 4; ++ni)
          acc[mi][ni] = mfma16(af[mi], bf[ni], acc[mi][ni]);
    }
  }
}

// ===================== QKV projection =====================
// z picks {Wq,Wk,Wv}. Writes [B,H,S,HD] bf16.
// Q pre-scaled by (1/sqrt(dk))*log2(e) so attention exp runs in base-2 domain.
__global__ __launch_bounds__(256) void gemm_qkv_kernel(
    const __bf16* __restrict__ xb,
    const __bf16* __restrict__ wq, const __bf16* __restrict__ wk, const __bf16* __restrict__ wv,
    const float* __restrict__ bq, const float* __restrict__ bk, const float* __restrict__ bv,
    __bf16* Qo, __bf16* Ko, __bf16* Vo) {
  __shared__ __bf16 As[128 * 64];
  __shared__ __bf16 Bs[128 * 64];
  int z = blockIdx.z;
  const __bf16* W = z == 0 ? wq : (z == 1 ? wk : wv);
  const float* bias = z == 0 ? bq : (z == 1 ? bk : bv);
  __bf16* out = z == 0 ? Qo : (z == 1 ? Ko : Vo);
  const float sc = (z == 0) ? 0.18033688011112042f : 1.0f;  // 0.125 * log2(e)
  int m0 = blockIdx.x * 128, n0 = blockIdx.y * 128;
  f4 acc[4][4];
  gemm_core(xb, W, m0, n0, As, Bs, acc);
  int t = threadIdx.x, lane = t & 63, w = t >> 6, wr = w >> 1, wc = w & 1;
  #pragma unroll
  for (int mi = 0; mi < 4; ++mi)
    #pragma unroll
    for (int ni = 0; ni < 4; ++ni)
      #pragma unroll
      for (int r = 0; r < 4; ++r) {
        int m = m0 + wr * 64 + mi * 16 + ((lane >> 4) << 2) + r;
        int n = n0 + wc * 64 + ni * 16 + (lane & 15);
        float v = (acc[mi][ni][r] + bias[n]) * sc;
        int b = m >> 11, s = m & 2047, h = n >> 6, hd = n & 63;
        out[(((size_t)(b * NHEAD + h)) * S_LEN + s) * HDIM + hd] = (__bf16)v;
      }
}

// ===================== output projection =====================
__global__ __launch_bounds__(256) void gemm_o_kernel(const __bf16* __restrict__ ctx,
                                                     const __bf16* __restrict__ wo,
                                                     const float* __restrict__ bo,
                                                     float* __restrict__ out) {
  __shared__ __bf16 As[128 * 64];
  __shared__ __bf16 Bs[128 * 64];
  int m0 = blockIdx.x * 128, n0 = blockIdx.y * 128;
  f4 acc[4][4];
  gemm_core(ctx, wo, m0, n0, As, Bs, acc);
  int t = threadIdx.x, lane = t & 63, w = t >> 6, wr = w >> 1, wc = w & 1;
  #pragma unroll
  for (int mi = 0; mi < 4; ++mi)
    #pragma unroll
    for (int ni = 0; ni < 4; ++ni)
      #pragma unroll
      for (int r = 0; r < 4; ++r) {
        int m = m0 + wr * 64 + mi * 16 + ((lane >> 4) << 2) + r;
        int n = n0 + wc * 64 + ni * 16 + (lane & 15);
        out[(size_t)m * D_DIM + n] = acc[mi][ni][r] + bo[n];
      }
}

// ===================== V transpose: [B,H,S,HD] -> [B,H,HD,S] =====================
__global__ __launch_bounds__(256) void transpose_v_kernel(const __bf16* __restrict__ V,
                                                          __bf16* __restrict__ Vt) {
  __shared__ __bf16 tile[64][72];
  int bh = blockIdx.y, s0 = blockIdx.x * 64;
  const __bf16* Vp = V + (size_t)bh * S_LEN * HDIM;
  __bf16* Vtp = Vt + (size_t)bh * HDIM * S_LEN;
  int t = threadIdx.x;
  #pragma unroll
  for (int i = 0; i < 4; ++i) {
    int q = t + i * 256;
    int row = q >> 4, c4 = (q & 15) * 4;
    b4 v = *reinterpret_cast<const b4*>(&Vp[(size_t)(s0 + row) * HDIM + c4]);
    *reinterpret_cast<b4*>(&tile[row][c4]) = v;
  }
  __syncthreads();
  #pragma unroll
  for (int i = 0; i < 4; ++i) {
    int q = t + i * 256;
    int d = q >> 4, s4 = (q & 15) * 4;
    b4 v;
    v.x = tile[s4 + 0][d]; v.y = tile[s4 + 1][d];
    v.z = tile[s4 + 2][d]; v.w = tile[s4 + 3][d];
    *reinterpret_cast<b4*>(&Vtp[(size_t)d * S_LEN + s0 + s4]) = v;
  }
}

// ===================== flash attention (kv-split-2, 8 waves) =====================
// grid (S/128, B*H), 512 threads = 8 waves: 4 q-subtiles (qs=w&3, 32 q each)
// x 2 kv-halves (grp=w>>2, 1024 kv each, private double-buffered K/V LDS).
// Swapped QK^T (A=K, B=Q) -> lane owns one q column; softmax in-register;
// P->bf16 via v_cvt_pk_bf16_f32 + v_permlane32_swap_b32; row-sum l computed by
// an extra ones-MFMA in PV (C row r = sum_k P[k][q] for every r -> sums[0]=l).
// All fragment/staging addresses hoisted + strength-reduced.
#define NTG 16  // kv tiles per group: 1024 / 64

// Build PV B-fragment for one 16-k slot from C-layout f32 P regs base..base+7.
// v_permlane32_swap_b32: vdst.lanes[32:63] <-> vsrc.lanes[0:31]. swap(A0,B0):
//   lo lane: A0 = A0_own,     B0 = A0 from hi partner
//   hi lane: A0 = B0 from lo, B0 = B0_own
// -> fragment words [A0, A1, B0, B1] for both halves.
#define MKFRAG(dst, st, base) do {                                   \
    unsigned int A0_ = pkbf((st)[(base)+0], (st)[(base)+1]);         \
    unsigned int A1_ = pkbf((st)[(base)+2], (st)[(base)+3]);         \
    unsigned int B0_ = pkbf((st)[(base)+4], (st)[(base)+5]);         \
    unsigned int B1_ = pkbf((st)[(base)+6], (st)[(base)+7]);         \
    asm("v_permlane32_swap_b32 %0, %1" : "+v"(A0_), "+v"(B0_));      \
    asm("v_permlane32_swap_b32 %0, %1" : "+v"(A1_), "+v"(B1_));      \
    u32x4 wv_; wv_.x = A0_; wv_.y = A1_; wv_.z = B0_; wv_.w = B1_;   \
    dst = __builtin_bit_cast(b8, wv_);                               \
  } while (0)

__global__ __launch_bounds__(512, 4) void attn_kernel(const __bf16* __restrict__ Q,
                                                      const __bf16* __restrict__ K,
                                                      const __bf16* __restrict__ Vt,
                                                      __bf16* __restrict__ ctx) {
  __shared__ __bf16 Ks[2][2][64 * 64];   // [grp][buf][kv][d], swizzled 128B rows
  __shared__ __bf16 Vs[2][2][64 * 64];   // [grp][buf][d][kv], swizzled 128B rows
  int t = threadIdx.x, lane = t & 63, w = t >> 6;
  int lane31 = lane & 31, hi = lane >> 5;
  int grp = w >> 2, qs = w & 3, t256 = t & 255;
  int bh = blockIdx.y, b = bh >> 3, h = bh & 7;
  int q = blockIdx.x * 128 + qs * 32 + lane31;   // this lane's q row
  const __bf16* Qp = Q + (size_t)bh * S_LEN * HDIM;
  const __bf16* Kp = K + (size_t)bh * S_LEN * HDIM;
  const __bf16* Vp = Vt + (size_t)bh * HDIM * S_LEN;
  const int kv0 = grp * (S_LEN / 2);

  // Q fragments (B-operand: col=q=lane31, k=d=ks*16+hi*8+e). Q pre-scaled.
  b8 qf[4];
  #pragma unroll
  for (int ks = 0; ks < 4; ++ks)
    qf[ks] = *reinterpret_cast<const b8*>(&Qp[(size_t)q * HDIM + ks * 16 + hi * 8]);

  // all-ones A fragment for the row-sum MFMA
  b8 ones;
  { u32x4 ov; ov.x = ov.y = ov.z = ov.w = 0x3F803F80u; ones = __builtin_bit_cast(b8, ov); }

  // hoisted fragment byte offsets (shared by K and V tiles; loop-invariant)
  int foff[8];
  #pragma unroll
  for (int half = 0; half < 2; ++half)
    #pragma unroll
    for (int ks = 0; ks < 4; ++ks) {
      int row = half * 32 + lane31;
      int bc = hi * 16 + ks * 32;
      foff[half * 4 + ks] = row * 128 + (bc ^ ((row & 7) << 4));
    }

  // hoisted staging addresses (strength-reduced per iteration)
  int oA = t256 * 16, oB = 4096 + t256 * 16;
  int rA = oA >> 7, rB = oB >> 7;
  int sA = (oA & 127) ^ ((rA & 7) << 4), sB = (oB & 127) ^ ((rB & 7) << 4);
  const char* KgA = (const char*)Kp + (size_t)(kv0 + rA) * 128 + sA;   // += 8192/iter
  const char* KgB = (const char*)Kp + (size_t)(kv0 + rB) * 128 + sB;
  const char* VgA = (const char*)Vp + (size_t)rA * (S_LEN * 2) + (size_t)kv0 * 2 + sA;  // += 128/iter
  const char* VgB = (const char*)Vp + (size_t)rB * (S_LEN * 2) + (size_t)kv0 * 2 + sB;
  char* KsB_ = (char*)&Ks[grp][0][0];
  char* VsB_ = (char*)&Vs[grp][0][0];

  const f16v Z16 = {0,0,0,0,0,0,0,0,0,0,0,0,0,0,0,0};
  f16v o0 = Z16, o1 = Z16;   // O^T accum: rows d (0-31 / 32-63), col q
  f16v sums = Z16;           // ones-MFMA row-sum accumulator; sums[0] = l
  float mr = -1e30f;

  auto stage = [&](int buf) {
    load_lds16(KgA, KsB_ + buf * 8192 + oA);
    load_lds16(KgB, KsB_ + buf * 8192 + oB);
    load_lds16(VgA, VsB_ + buf * 8192 + oA);
    load_lds16(VgB, VsB_ + buf * 8192 + oB);
    KgA += 8192; KgB += 8192; VgA += 128; VgB += 128;
  };

  stage(0);
  __syncthreads();
  int cur = 0;

  for (int it = 0; it < NTG; ++it) {
    if (it + 1 < NTG) stage(cur ^ 1);

    const char* KsT = KsB_ + cur * 8192;
    const char* VsT = VsB_ + cur * 8192;

    // S^T = K * Q^T: t0 (kv+0..31), t1 (kv+32..63); lane: col q, rows kv
    f16v t0 = Z16, t1 = Z16;
    __builtin_amdgcn_s_setprio(1);
    #pragma unroll
    for (int ks = 0; ks < 4; ++ks) {
      b8 kf0 = *reinterpret_cast<const b8*>(KsT + foff[ks]);
      b8 kf1 = *reinterpret_cast<const b8*>(KsT + foff[4 + ks]);
      t0 = mfma32(kf0, qf[ks], t0);
      t1 = mfma32(kf1, qf[ks], t1);
    }
    __builtin_amdgcn_s_setprio(0);

    // balanced row-max over 64 kv (max3-fusible) + cross-half exchange
    float a0 = fmaxf(fmaxf(t0[0], t0[8]),  fmaxf(t1[0], t1[8]));
    float a1 = fmaxf(fmaxf(t0[1], t0[9]),  fmaxf(t1[1], t1[9]));
    float a2 = fmaxf(fmaxf(t0[2], t0[10]), fmaxf(t1[2], t1[10]));
    float a3 = fmaxf(fmaxf(t0[3], t0[11]), fmaxf(t1[3], t1[11]));
    float a4 = fmaxf(fmaxf(t0[4], t0[12]), fmaxf(t1[4], t1[12]));
    float a5 = fmaxf(fmaxf(t0[5], t0[13]), fmaxf(t1[5], t1[13]));
    float a6 = fmaxf(fmaxf(t0[6], t0[14]), fmaxf(t1[6], t1[14]));
    float a7 = fmaxf(fmaxf(t0[7], t0[15]), fmaxf(t1[7], t1[15]));
    float mx = fmaxf(fmaxf(fmaxf(a0, a1), fmaxf(a2, a3)),
                     fmaxf(fmaxf(a4, a5), fmaxf(a6, a7)));
    mx = fmaxf(mx, __shfl_xor(mx, 32));

    // defer-max (base-2): rescale only when max grew by > 11.5 (~8 nats)
    if (!__all(mx - mr <= 11.5f)) {
      float mn = fmaxf(mr, mx);
      float al = exp2v(mr - mn);
      mr = mn;
      sums[0] *= al;
      o0 *= al;
      o1 *= al;
    }

    // P = 2^(S2 - m2) in place (row sum comes from the ones-MFMA)
    #pragma unroll
    for (int r = 0; r < 16; ++r) t0[r] = exp2v(t0[r] - mr);
    #pragma unroll
    for (int r = 0; r < 16; ++r) t1[r] = exp2v(t1[r] - mr);

    // pack P to bf16 PV B-fragments (k-slots over kv)
    b8 pa[4];
    MKFRAG(pa[0], t0, 0);
    MKFRAG(pa[1], t0, 8);
    MKFRAG(pa[2], t1, 0);
    MKFRAG(pa[3], t1, 8);

    // O^T += V^T * P^T ; sums += ones * P^T (row-sum = l, on the MFMA pipe)
    __builtin_amdgcn_s_setprio(1);
    #pragma unroll
    for (int ks = 0; ks < 4; ++ks) {
      b8 vf0 = *reinterpret_cast<const b8*>(VsT + foff[ks]);
      b8 vf1 = *reinterpret_cast<const b8*>(VsT + foff[4 + ks]);
      o0 = mfma32(vf0, pa[ks], o0);
      o1 = mfma32(vf1, pa[ks], o1);
      sums = mfma32(ones, pa[ks], sums);
    }
    __builtin_amdgcn_s_setprio(0);

    __syncthreads();  // drain prefetch vmcnt + all waves done reading buf[cur]
    cur ^= 1;
  }

  // ---- merge the two kv-halves (grp1 -> LDS -> grp0), then write ctx ----
  float l_own = sums[0];   // covers all 64 kv columns (both lane halves)
  float* OL = (float*)&Ks[0][0][0];   // [4 qs][64 d][32 q] f32 = 32 KiB (staging dead)
  float* ML = OL + 8192;              // m[4][32] then l[4][32]
  if (grp == 1) {
    #pragma unroll
    for (int g = 0; g < 4; ++g)
      #pragma unroll
      for (int j = 0; j < 4; ++j) {
        int d = 8 * g + 4 * hi + j;
        OL[(qs * 64 + d) * 32 + lane31]      = o0[4 * g + j];
        OL[(qs * 64 + 32 + d) * 32 + lane31] = o1[4 * g + j];
      }
    if (hi == 0) { ML[qs * 32 + lane31] = mr; ML[128 + qs * 32 + lane31] = l_own; }
  }
  __syncthreads();
  if (grp == 0) {
    float m1 = ML[qs * 32 + lane31], l1 = ML[128 + qs * 32 + lane31];
    float mm = fmaxf(mr, m1);
    float s0 = exp2v(mr - mm), s1 = exp2v(m1 - mm);
    float inv = 1.0f / (l_own * s0 + l1 * s1);
    __bf16* cp = ctx + (size_t)b * S_LEN * D_DIM + (size_t)q * D_DIM + (size_t)h * HDIM;
    #pragma unroll
    for (int g = 0; g < 4; ++g) {
      b4 v0, v1;
      #pragma unroll
      for (int j = 0; j < 4; ++j) {
        int d = 8 * g + 4 * hi + j;
        v0[j] = (__bf16)((o0[4 * g + j] * s0 + OL[(qs * 64 + d) * 32 + lane31] * s1) * inv);
        v1[j] = (__bf16)((o1[4 * g + j] * s0 + OL[(qs * 64 + 32 + d) * 32 + lane31] * s1) * inv);
      }
      int d0 = 8 * g + 4 * hi;
      *reinterpret_cast<b4*>(cp + d0)      = v0;
      *reinterpret_cast<b4*>(cp + 32 + d0) = v1;
    }
  }
}

// ===================== launch =====================
extern "C" void kernel_launch(void* const* d_in, const int* in_sizes, int n_in,
                              void* d_out, int out_size, void* d_ws, size_t ws_size,
                              hipStream_t stream) {
  const float* x  = (const float*)d_in[0];
  const float* Wq = (const float*)d_in[1];
  const float* bq = (const float*)d_in[2];
  const float* Wk = (const float*)d_in[3];
  const float* bk = (const float*)d_in[4];
  const float* Wv = (const float*)d_in[5];
  const float* bv = (const float*)d_in[6];
  const float* Wo = (const float*)d_in[7];
  const float* bo = (const float*)d_in[8];
  float* out = (float*)d_out;

  char* ws = (char*)d_ws;
  __bf16* xb   = (__bf16*)(ws);                               // 8192*512
  __bf16* wqb  = xb  + 4194304;                               // 512*512
  __bf16* wkb  = wqb + 262144;
  __bf16* wvb  = wkb + 262144;
  __bf16* wob  = wvb + 262144;
  __bf16* Qb   = wob + 262144;                                // 4*8*2048*64
  __bf16* Kb   = Qb  + 4194304;
  __bf16* Vb   = Kb  + 4194304;
  __bf16* Vtb  = Vb  + 4194304;
  __bf16* ctxb = xb;  // reuse (x dead after QKV)

  cvt_kernel<<<dim3(4096), dim3(256), 0, stream>>>(x, xb);
  cvt_w_kernel<<<dim3(256, 4), dim3(256), 0, stream>>>(Wq, Wk, Wv, Wo, wqb, wkb, wvb, wob);
  gemm_qkv_kernel<<<dim3(64, 4, 3), dim3(256), 0, stream>>>(xb, wqb, wkb, wvb, bq, bk, bv, Qb, Kb, Vb);
  transpose_v_kernel<<<dim3(32, 32), dim3(256), 0, stream>>>(Vb, Vtb);
  attn_kernel<<<dim3(16, 32), dim3(512), 0, stream>>>(Qb, Kb, Vtb, ctxb);
  gemm_o_kernel<<<dim3(64, 4), dim3(256), 0, stream>>>(ctxb, wob, bo, out);
}

// Round 7
// 105.928 us; speedup vs baseline: 1.7408x; 1.0218x over previous
//
#include <hip/hip_runtime.h>
#include <hip/hip_bf16.h>
#include <cstdint>
#include <cstddef>

// Problem dims (fixed): B=4, S=2048, D=512, H=8, HD=64, M = B*S = 8192
#define S_LEN 2048
#define D_DIM 512
#define NHEAD 8
#define HDIM  64

typedef __attribute__((ext_vector_type(8)))  __bf16 b8;    // MFMA A/B fragment (4 VGPRs)
typedef __attribute__((ext_vector_type(4)))  __bf16 b4;    // 8-byte vector
typedef __attribute__((ext_vector_type(4)))  float  f4;    // 16x16 C fragment
typedef __attribute__((ext_vector_type(16))) float  f16v;  // 32x32 C fragment
typedef __attribute__((ext_vector_type(4)))  unsigned int u32x4;

#define AS_GLOBAL __attribute__((address_space(1)))
#define AS_LDS    __attribute__((address_space(3)))

__device__ __forceinline__ void load_lds16(const void* g, void* l) {
  __builtin_amdgcn_global_load_lds((const AS_GLOBAL void*)g, (AS_LDS void*)l, 16, 0, 0);
}

__device__ __forceinline__ f4 mfma16(b8 a, b8 b, f4 c) {
  return __builtin_amdgcn_mfma_f32_16x16x32_bf16(a, b, c, 0, 0, 0);
}
__device__ __forceinline__ f16v mfma32(b8 a, b8 b, f16v c) {
  return __builtin_amdgcn_mfma_f32_32x32x16_bf16(a, b, c, 0, 0, 0);
}

// single-instruction 2^x
__device__ __forceinline__ float exp2v(float x) {
#if __has_builtin(__builtin_amdgcn_exp2f)
  return __builtin_amdgcn_exp2f(x);
#else
  float r; asm("v_exp_f32 %0, %1" : "=v"(r) : "v"(x)); return r;
#endif
}

// v_cvt_pk_bf16_f32: D.lo = bf16(S0), D.hi = bf16(S1)
__device__ __forceinline__ unsigned int pkbf(float lo, float hi_) {
  unsigned int r;
  asm("v_cvt_pk_bf16_f32 %0, %1, %2" : "=v"(r) : "v"(lo), "v"(hi_));
  return r;
}

// Swizzled read from an LDS tile with 128-byte rows. Physical byte =
// row*128 + (bytecol ^ ((row&7)<<4)); staging pre-applies the same XOR to the
// global source column so logical data lands in the right slot (involution).
__device__ __forceinline__ b8 lds_frag(const __bf16* base, int row, int bc) {
  return *reinterpret_cast<const b8*>((const char*)base + row * 128 + (bc ^ ((row & 7) << 4)));
}

// ===================== fp32 -> bf16 conversion =====================
__global__ __launch_bounds__(256) void cvt_kernel(const float* __restrict__ in,
                                                  __bf16* __restrict__ out) {
  int i = (blockIdx.x * 256 + threadIdx.x) * 4;
  float4 v = *reinterpret_cast<const float4*>(in + i);
  b4 o;
  o.x = (__bf16)v.x; o.y = (__bf16)v.y; o.z = (__bf16)v.z; o.w = (__bf16)v.w;
  *reinterpret_cast<b4*>(out + i) = o;
}

__global__ __launch_bounds__(256) void cvt_w_kernel(const float* __restrict__ w0, const float* __restrict__ w1,
                                                    const float* __restrict__ w2, const float* __restrict__ w3,
                                                    __bf16* o0, __bf16* o1, __bf16* o2, __bf16* o3) {
  const float* in = blockIdx.y == 0 ? w0 : blockIdx.y == 1 ? w1 : blockIdx.y == 2 ? w2 : w3;
  __bf16* out     = blockIdx.y == 0 ? o0 : blockIdx.y == 1 ? o1 : blockIdx.y == 2 ? o2 : o3;
  int i = (blockIdx.x * 256 + threadIdx.x) * 4;
  float4 v = *reinterpret_cast<const float4*>(in + i);
  b4 o;
  o.x = (__bf16)v.x; o.y = (__bf16)v.y; o.z = (__bf16)v.z; o.w = (__bf16)v.w;
  *reinterpret_cast<b4*>(out + i) = o;
}

// ===================== GEMM core: C(128x128) = A * W^T =====================
__device__ __forceinline__ void gemm_core(const __bf16* __restrict__ A, const __bf16* __restrict__ W,
                                          int m0, int n0, __bf16* As, __bf16* Bs, f4 acc[4][4]) {
  const int t = threadIdx.x;
  const int lane = t & 63;
  const int w = t >> 6, wr = w >> 1, wc = w & 1;
  const f4 zero = {0.f, 0.f, 0.f, 0.f};
  #pragma unroll
  for (int mi = 0; mi < 4; ++mi)
    #pragma unroll
    for (int ni = 0; ni < 4; ++ni) acc[mi][ni] = zero;

  const char* Ab = (const char*)A;
  const char* Wb = (const char*)W;
  for (int kt = 0; kt < 512; kt += 64) {
    __syncthreads();
    #pragma unroll
    for (int i = 0; i < 4; ++i) {
      int o = i * 4096 + t * 16;
      int row = o >> 7, cb = o & 127;
      int scb = cb ^ ((row & 7) << 4);
      load_lds16(Ab + ((size_t)(m0 + row) * 512 + kt) * 2 + scb, (char*)As + o);
      load_lds16(Wb + ((size_t)(n0 + row) * 512 + kt) * 2 + scb, (char*)Bs + o);
    }
    __syncthreads();
    #pragma unroll
    for (int kk = 0; kk < 2; ++kk) {
      b8 af[4], bf[4];
      #pragma unroll
      for (int mi = 0; mi < 4; ++mi)
        af[mi] = lds_frag(As, wr * 64 + mi * 16 + (lane & 15), kk * 64 + ((lane >> 4) << 4));
      #pragma unroll
      for (int ni = 0; ni < 4; ++ni)
        bf[ni] = lds_frag(Bs, wc * 64 + ni * 16 + (lane & 15), kk * 64 + ((lane >> 4) << 4));
      #pragma unroll
      for (int mi = 0; mi < 4; ++mi)
        #pragma unroll
        for (int ni = 0; ni < 4; ++ni)
          acc[mi][ni] = mfma16(af[mi], bf[ni], acc[mi][ni]);
    }
  }
}

// ===================== QKV projection =====================
// z picks {Wq,Wk,Wv}. Writes [B,H,S,HD] bf16.
// Q pre-scaled by (1/sqrt(dk))*log2(e) so attention exp runs in base-2 domain.
__global__ __launch_bounds__(256) void gemm_qkv_kernel(
    const __bf16* __restrict__ xb,
    const __bf16* __restrict__ wq, const __bf16* __restrict__ wk, const __bf16* __restrict__ wv,
    const float* __restrict__ bq, const float* __restrict__ bk, const float* __restrict__ bv,
    __bf16* Qo, __bf16* Ko, __bf16* Vo) {
  __shared__ __bf16 As[128 * 64];
  __shared__ __bf16 Bs[128 * 64];
  int z = blockIdx.z;
  const __bf16* W = z == 0 ? wq : (z == 1 ? wk : wv);
  const float* bias = z == 0 ? bq : (z == 1 ? bk : bv);
  __bf16* out = z == 0 ? Qo : (z == 1 ? Ko : Vo);
  const float sc = (z == 0) ? 0.18033688011112042f : 1.0f;  // 0.125 * log2(e)
  int m0 = blockIdx.x * 128, n0 = blockIdx.y * 128;
  f4 acc[4][4];
  gemm_core(xb, W, m0, n0, As, Bs, acc);
  int t = threadIdx.x, lane = t & 63, w = t >> 6, wr = w >> 1, wc = w & 1;
  #pragma unroll
  for (int mi = 0; mi < 4; ++mi)
    #pragma unroll
    for (int ni = 0; ni < 4; ++ni)
      #pragma unroll
      for (int r = 0; r < 4; ++r) {
        int m = m0 + wr * 64 + mi * 16 + ((lane >> 4) << 2) + r;
        int n = n0 + wc * 64 + ni * 16 + (lane & 15);
        float v = (acc[mi][ni][r] + bias[n]) * sc;
        int b = m >> 11, s = m & 2047, h = n >> 6, hd = n & 63;
        out[(((size_t)(b * NHEAD + h)) * S_LEN + s) * HDIM + hd] = (__bf16)v;
      }
}

// ===================== output projection =====================
__global__ __launch_bounds__(256) void gemm_o_kernel(const __bf16* __restrict__ ctx,
                                                     const __bf16* __restrict__ wo,
                                                     const float* __restrict__ bo,
                                                     float* __restrict__ out) {
  __shared__ __bf16 As[128 * 64];
  __shared__ __bf16 Bs[128 * 64];
  int m0 = blockIdx.x * 128, n0 = blockIdx.y * 128;
  f4 acc[4][4];
  gemm_core(ctx, wo, m0, n0, As, Bs, acc);
  int t = threadIdx.x, lane = t & 63, w = t >> 6, wr = w >> 1, wc = w & 1;
  #pragma unroll
  for (int mi = 0; mi < 4; ++mi)
    #pragma unroll
    for (int ni = 0; ni < 4; ++ni)
      #pragma unroll
      for (int r = 0; r < 4; ++r) {
        int m = m0 + wr * 64 + mi * 16 + ((lane >> 4) << 2) + r;
        int n = n0 + wc * 64 + ni * 16 + (lane & 15);
        out[(size_t)m * D_DIM + n] = acc[mi][ni][r] + bo[n];
      }
}

// ===================== V transpose: [B,H,S,HD] -> [B,H,HD,S] =====================
__global__ __launch_bounds__(256) void transpose_v_kernel(const __bf16* __restrict__ V,
                                                          __bf16* __restrict__ Vt) {
  __shared__ __bf16 tile[64][72];
  int bh = blockIdx.y, s0 = blockIdx.x * 64;
  const __bf16* Vp = V + (size_t)bh * S_LEN * HDIM;
  __bf16* Vtp = Vt + (size_t)bh * HDIM * S_LEN;
  int t = threadIdx.x;
  #pragma unroll
  for (int i = 0; i < 4; ++i) {
    int q = t + i * 256;
    int row = q >> 4, c4 = (q & 15) * 4;
    b4 v = *reinterpret_cast<const b4*>(&Vp[(size_t)(s0 + row) * HDIM + c4]);
    *reinterpret_cast<b4*>(&tile[row][c4]) = v;
  }
  __syncthreads();
  #pragma unroll
  for (int i = 0; i < 4; ++i) {
    int q = t + i * 256;
    int d = q >> 4, s4 = (q & 15) * 4;
    b4 v;
    v.x = tile[s4 + 0][d]; v.y = tile[s4 + 1][d];
    v.z = tile[s4 + 2][d]; v.w = tile[s4 + 3][d];
    *reinterpret_cast<b4*>(&Vtp[(size_t)d * S_LEN + s0 + s4]) = v;
  }
}

// ===================== flash attention (kv-split-2, 8 waves) =====================
// 1-D grid 512 blocks, XCD-swizzled so each XCD owns 4 whole heads (K/V L2-resident).
// 512 threads = 8 waves: 4 q-subtiles (qs, 32 q) x 2 kv-halves (grp, 1024 kv each,
// private double-buffered K/V in one fused smem block). Swapped QK^T (A=K, B=Q);
// softmax in-register; P->bf16 via cvt_pk + permlane32_swap, ONE fragment at a
// time interleaved with its PV MFMAs (low reg pressure); row-sum l via ones-MFMA.
// kv loop unrolled x2 -> all ds_read offsets are compile-time immediates.
//
// smem layout (bytes): K tiles [grp*16384 + buf*8192, +8192) ; V at +32768.
#define NTG 16  // kv tiles per group: 1024 / 64

// Build PV B-fragment for one 16-k slot from C-layout f32 P regs base..base+7.
// v_permlane32_swap_b32: vdst.lanes[32:63] <-> vsrc.lanes[0:31]. swap(A0,B0):
//   lo lane: A0 = A0_own,     B0 = A0 from hi partner
//   hi lane: A0 = B0 from lo, B0 = B0_own
// -> fragment words [A0, A1, B0, B1] for both halves.
#define MKFRAG(dst, st, base) do {                                   \
    unsigned int A0_ = pkbf((st)[(base)+0], (st)[(base)+1]);         \
    unsigned int A1_ = pkbf((st)[(base)+2], (st)[(base)+3]);         \
    unsigned int B0_ = pkbf((st)[(base)+4], (st)[(base)+5]);         \
    unsigned int B1_ = pkbf((st)[(base)+6], (st)[(base)+7]);         \
    asm("v_permlane32_swap_b32 %0, %1" : "+v"(A0_), "+v"(B0_));      \
    asm("v_permlane32_swap_b32 %0, %1" : "+v"(A1_), "+v"(B1_));      \
    u32x4 wv_; wv_.x = A0_; wv_.y = A1_; wv_.z = B0_; wv_.w = B1_;   \
    dst = __builtin_bit_cast(b8, wv_);                               \
  } while (0)

// One 64-kv tile. KO/VO are compile-time byte offsets of the K / V tiles.
#define TILE(KO, VO) do {                                                     \
    f16v t0 = Z16, t1 = Z16;                                                  \
    __builtin_amdgcn_s_setprio(1);                                            \
    _Pragma("unroll")                                                         \
    for (int ks = 0; ks < 4; ++ks) {                                          \
      b8 kf0 = *reinterpret_cast<const AS_LDS b8*>(sb + koff[ks] + (KO));     \
      b8 kf1 = *reinterpret_cast<const AS_LDS b8*>(sb + koff[ks] + (KO) + 4096); \
      t0 = mfma32(kf0, qf[ks], t0);                                           \
      t1 = mfma32(kf1, qf[ks], t1);                                           \
    }                                                                         \
    __builtin_amdgcn_s_setprio(0);                                            \
    float a0 = fmaxf(fmaxf(t0[0], t0[8]),  fmaxf(t1[0], t1[8]));              \
    float a1 = fmaxf(fmaxf(t0[1], t0[9]),  fmaxf(t1[1], t1[9]));              \
    float a2 = fmaxf(fmaxf(t0[2], t0[10]), fmaxf(t1[2], t1[10]));             \
    float a3 = fmaxf(fmaxf(t0[3], t0[11]), fmaxf(t1[3], t1[11]));             \
    float a4 = fmaxf(fmaxf(t0[4], t0[12]), fmaxf(t1[4], t1[12]));             \
    float a5 = fmaxf(fmaxf(t0[5], t0[13]), fmaxf(t1[5], t1[13]));             \
    float a6 = fmaxf(fmaxf(t0[6], t0[14]), fmaxf(t1[6], t1[14]));             \
    float a7 = fmaxf(fmaxf(t0[7], t0[15]), fmaxf(t1[7], t1[15]));             \
    float mx = fmaxf(fmaxf(fmaxf(a0, a1), fmaxf(a2, a3)),                     \
                     fmaxf(fmaxf(a4, a5), fmaxf(a6, a7)));                    \
    mx = fmaxf(mx, __shfl_xor(mx, 32));                                       \
    if (!__all(mx - mr <= 11.5f)) {                                           \
      float mn = fmaxf(mr, mx);                                               \
      float al = exp2v(mr - mn);                                              \
      mr = mn; sums[0] *= al; o0 *= al; o1 *= al;                             \
    }                                                                         \
    _Pragma("unroll")                                                         \
    for (int r = 0; r < 16; ++r) t0[r] = exp2v(t0[r] - mr);                   \
    _Pragma("unroll")                                                         \
    for (int r = 0; r < 16; ++r) t1[r] = exp2v(t1[r] - mr);                   \
    __builtin_amdgcn_s_setprio(1);                                            \
    _Pragma("unroll")                                                         \
    for (int ks = 0; ks < 4; ++ks) {                                          \
      b8 pa;                                                                  \
      if (ks == 0)      MKFRAG(pa, t0, 0);                                    \
      else if (ks == 1) MKFRAG(pa, t0, 8);                                    \
      else if (ks == 2) MKFRAG(pa, t1, 0);                                    \
      else              MKFRAG(pa, t1, 8);                                    \
      b8 vf0 = *reinterpret_cast<const AS_LDS b8*>(sb + koff[ks] + (VO));     \
      b8 vf1 = *reinterpret_cast<const AS_LDS b8*>(sb + koff[ks] + (VO) + 4096); \
      o0 = mfma32(vf0, pa, o0);                                               \
      o1 = mfma32(vf1, pa, o1);                                               \
      sums = mfma32(ones, pa, sums);                                          \
    }                                                                         \
    __builtin_amdgcn_s_setprio(0);                                            \
  } while (0)

__global__ __launch_bounds__(512, 4) void attn_kernel(const __bf16* __restrict__ Q,
                                                      const __bf16* __restrict__ K,
                                                      const __bf16* __restrict__ Vt,
                                                      __bf16* __restrict__ ctx) {
  __shared__ char smem_[65536];
  int t = threadIdx.x, lane = t & 63, w = t >> 6;
  int lane31 = lane & 31, hi = lane >> 5;
  int grp = w >> 2, qs = w & 3, t256 = t & 255;

  // XCD swizzle: 512 blocks, 8 XCDs -> 64-block contiguous chunk per XCD
  // = 4 whole heads per XCD (16 q-tiles x same bh -> K/V L2-resident).
  int bid = blockIdx.x;
  int nid = (bid & 7) * 64 + (bid >> 3);
  int bh = nid >> 4, qtile = nid & 15;
  int b = bh >> 3, h = bh & 7;
  int q = qtile * 128 + qs * 32 + lane31;   // this lane's q row
  const __bf16* Qp = Q + (size_t)bh * S_LEN * HDIM;
  const __bf16* Kp = K + (size_t)bh * S_LEN * HDIM;
  const __bf16* Vp = Vt + (size_t)bh * HDIM * S_LEN;
  const int kv0 = grp * (S_LEN / 2);

  // Q fragments (B-operand: col=q=lane31, k=d=ks*16+hi*8+e). Q pre-scaled.
  b8 qf[4];
  #pragma unroll
  for (int ks = 0; ks < 4; ++ks)
    qf[ks] = *reinterpret_cast<const b8*>(&Qp[(size_t)q * HDIM + ks * 16 + hi * 8]);

  // all-ones A fragment for the row-sum MFMA
  b8 ones;
  { u32x4 ov; ov.x = ov.y = ov.z = ov.w = 0x3F803F80u; ones = __builtin_bit_cast(b8, ov); }

  // 32-bit LDS base + per-ks fragment offsets (half1 = +4096 immediate since
  // (row+32)&7 == row&7). koff folds in grp*16384.
  const AS_LDS char* sb = (const AS_LDS char*)smem_;
  unsigned koff[4];
  #pragma unroll
  for (int ks = 0; ks < 4; ++ks) {
    int bc = hi * 16 + ks * 32;
    koff[ks] = grp * 16384 + lane31 * 128 + (bc ^ ((lane31 & 7) << 4));
  }

  // staging addresses (strength-reduced per iteration)
  int oA = t256 * 16, oB = 4096 + t256 * 16;
  int rA = oA >> 7, rB = oB >> 7;
  int sA = (oA & 127) ^ ((rA & 7) << 4), sB = (oB & 127) ^ ((rB & 7) << 4);
  const char* KgA = (const char*)Kp + (size_t)(kv0 + rA) * 128 + sA;   // += 8192/iter
  const char* KgB = (const char*)Kp + (size_t)(kv0 + rB) * 128 + sB;
  const char* VgA = (const char*)Vp + (size_t)rA * (S_LEN * 2) + (size_t)kv0 * 2 + sA;  // += 128/iter
  const char* VgB = (const char*)Vp + (size_t)rB * (S_LEN * 2) + (size_t)kv0 * 2 + sB;

  const f16v Z16 = {0,0,0,0,0,0,0,0,0,0,0,0,0,0,0,0};
  f16v o0 = Z16, o1 = Z16;   // O^T accum: rows d (0-31 / 32-63), col q
  f16v sums = Z16;           // ones-MFMA row-sum accumulator; sums[0] = l
  float mr = -1e30f;

  auto stage = [&](int buf) {
    char* ldsK = smem_ + grp * 16384 + buf * 8192;
    load_lds16(KgA, ldsK + oA);
    load_lds16(KgB, ldsK + oB);
    load_lds16(VgA, ldsK + 32768 + oA);
    load_lds16(VgB, ldsK + 32768 + oB);
    KgA += 8192; KgB += 8192; VgA += 128; VgB += 128;
  };

  stage(0);
  __syncthreads();

  #pragma unroll 1
  for (int it2 = 0; it2 < NTG / 2; ++it2) {
    stage(1);
    TILE(0, 32768);
    __syncthreads();
    if (it2 < NTG / 2 - 1) stage(0);
    TILE(8192, 40960);
    __syncthreads();
  }

  // ---- merge the two kv-halves (grp1 -> LDS -> grp0), then write ctx ----
  float l_own = sums[0];   // covers all 64 kv columns (both lane halves)
  float* OL = (float*)smem_;          // [4 qs][64 d][32 q] f32 = 32 KiB (staging dead)
  float* ML = OL + 8192;              // m[4][32] then l[4][32]
  if (grp == 1) {
    #pragma unroll
    for (int g = 0; g < 4; ++g)
      #pragma unroll
      for (int j = 0; j < 4; ++j) {
        int d = 8 * g + 4 * hi + j;
        OL[(qs * 64 + d) * 32 + lane31]      = o0[4 * g + j];
        OL[(qs * 64 + 32 + d) * 32 + lane31] = o1[4 * g + j];
      }
    if (hi == 0) { ML[qs * 32 + lane31] = mr; ML[128 + qs * 32 + lane31] = l_own; }
  }
  __syncthreads();
  if (grp == 0) {
    float m1 = ML[qs * 32 + lane31], l1 = ML[128 + qs * 32 + lane31];
    float mm = fmaxf(mr, m1);
    float s0 = exp2v(mr - mm), s1 = exp2v(m1 - mm);
    float inv = 1.0f / (l_own * s0 + l1 * s1);
    __bf16* cp = ctx + (size_t)b * S_LEN * D_DIM + (size_t)q * D_DIM + (size_t)h * HDIM;
    #pragma unroll
    for (int g = 0; g < 4; ++g) {
      b4 v0, v1;
      #pragma unroll
      for (int j = 0; j < 4; ++j) {
        int d = 8 * g + 4 * hi + j;
        v0[j] = (__bf16)((o0[4 * g + j] * s0 + OL[(qs * 64 + d) * 32 + lane31] * s1) * inv);
        v1[j] = (__bf16)((o1[4 * g + j] * s0 + OL[(qs * 64 + 32 + d) * 32 + lane31] * s1) * inv);
      }
      int d0 = 8 * g + 4 * hi;
      *reinterpret_cast<b4*>(cp + d0)      = v0;
      *reinterpret_cast<b4*>(cp + 32 + d0) = v1;
    }
  }
}

// ===================== launch =====================
extern "C" void kernel_launch(void* const* d_in, const int* in_sizes, int n_in,
                              void* d_out, int out_size, void* d_ws, size_t ws_size,
                              hipStream_t stream) {
  const float* x  = (const float*)d_in[0];
  const float* Wq = (const float*)d_in[1];
  const float* bq = (const float*)d_in[2];
  const float* Wk = (const float*)d_in[3];
  const float* bk = (const float*)d_in[4];
  const float* Wv = (const float*)d_in[5];
  const float* bv = (const float*)d_in[6];
  const float* Wo = (const float*)d_in[7];
  const float* bo = (const float*)d_in[8];
  float* out = (float*)d_out;

  char* ws = (char*)d_ws;
  __bf16* xb   = (__bf16*)(ws);                               // 8192*512
  __bf16* wqb  = xb  + 4194304;                               // 512*512
  __bf16* wkb  = wqb + 262144;
  __bf16* wvb  = wkb + 262144;
  __bf16* wob  = wvb + 262144;
  __bf16* Qb   = wob + 262144;                                // 4*8*2048*64
  __bf16* Kb   = Qb  + 4194304;
  __bf16* Vb   = Kb  + 4194304;
  __bf16* Vtb  = Vb  + 4194304;
  __bf16* ctxb = xb;  // reuse (x dead after QKV)

  cvt_kernel<<<dim3(4096), dim3(256), 0, stream>>>(x, xb);
  cvt_w_kernel<<<dim3(256, 4), dim3(256), 0, stream>>>(Wq, Wk, Wv, Wo, wqb, wkb, wvb, wob);
  gemm_qkv_kernel<<<dim3(64, 4, 3), dim3(256), 0, stream>>>(xb, wqb, wkb, wvb, bq, bk, bv, Qb, Kb, Vb);
  transpose_v_kernel<<<dim3(32, 32), dim3(256), 0, stream>>>(Vb, Vtb);
  attn_kernel<<<dim3(512), dim3(512), 0, stream>>>(Qb, Kb, Vtb, ctxb);
  gemm_o_kernel<<<dim3(64, 4), dim3(256), 0, stream>>>(ctxb, wob, bo, out);
}

// Round 10
// 101.982 us; speedup vs baseline: 1.8082x; 1.0387x over previous
//
#include <hip/hip_runtime.h>
#include <hip/hip_bf16.h>
#include <cstdint>
#include <cstddef>

// Problem dims (fixed): B=4, S=2048, D=512, H=8, HD=64, M = B*S = 8192
#define S_LEN 2048
#define D_DIM 512
#define NHEAD 8
#define HDIM  64

typedef __attribute__((ext_vector_type(8)))  __bf16 b8;    // MFMA A/B fragment (4 VGPRs)
typedef __attribute__((ext_vector_type(4)))  __bf16 b4;    // 8-byte vector
typedef __attribute__((ext_vector_type(4)))  float  f4;    // 16x16 C fragment
typedef __attribute__((ext_vector_type(16))) float  f16v;  // 32x32 C fragment
typedef __attribute__((ext_vector_type(4)))  unsigned int u32x4;

#define AS_GLOBAL __attribute__((address_space(1)))
#define AS_LDS    __attribute__((address_space(3)))

__device__ __forceinline__ void load_lds16(const void* g, void* l) {
  __builtin_amdgcn_global_load_lds((const AS_GLOBAL void*)g, (AS_LDS void*)l, 16, 0, 0);
}

__device__ __forceinline__ f4 mfma16(b8 a, b8 b, f4 c) {
  return __builtin_amdgcn_mfma_f32_16x16x32_bf16(a, b, c, 0, 0, 0);
}
__device__ __forceinline__ f16v mfma32(b8 a, b8 b, f16v c) {
  return __builtin_amdgcn_mfma_f32_32x32x16_bf16(a, b, c, 0, 0, 0);
}

// single-instruction 2^x
__device__ __forceinline__ float exp2v(float x) {
#if __has_builtin(__builtin_amdgcn_exp2f)
  return __builtin_amdgcn_exp2f(x);
#else
  float r; asm("v_exp_f32 %0, %1" : "=v"(r) : "v"(x)); return r;
#endif
}

// v_cvt_pk_bf16_f32: D.lo = bf16(S0), D.hi = bf16(S1)
__device__ __forceinline__ unsigned int pkbf(float lo, float hi_) {
  unsigned int r;
  asm("v_cvt_pk_bf16_f32 %0, %1, %2" : "=v"(r) : "v"(lo), "v"(hi_));
  return r;
}

// cross-half (lane i <-> lane i^32) combine. NOTE (R7/R8 post-mortem): a
// self-exchange via v_permlane32_swap inside one asm block reads stale
// registers (permlane consumes a VGPR written by the IMMEDIATELY preceding
// VALU op; compiler inserts the hazard wait-states only for intrinsics, not
// inside inline asm). Use the proven shfl_xor (ds_bpermute) forms; permlane
// is safe only in the MKFRAG pattern where producers are compiler-scheduled.
__device__ __forceinline__ float xhalf_max(float v) {
  return fmaxf(v, __shfl_xor(v, 32));
}
__device__ __forceinline__ float xhalf_add(float v) {
  return v + __shfl_xor(v, 32);
}

// Swizzled read from an LDS tile with 128-byte rows. Physical byte =
// row*128 + (bytecol ^ ((row&7)<<4)); staging pre-applies the same XOR to the
// global source column so logical data lands in the right slot (involution).
__device__ __forceinline__ b8 lds_frag(const __bf16* base, int row, int bc) {
  return *reinterpret_cast<const b8*>((const char*)base + row * 128 + (bc ^ ((row & 7) << 4)));
}

// ===================== fp32 -> bf16 conversion =====================
__global__ __launch_bounds__(256) void cvt_kernel(const float* __restrict__ in,
                                                  __bf16* __restrict__ out) {
  int i = (blockIdx.x * 256 + threadIdx.x) * 4;
  float4 v = *reinterpret_cast<const float4*>(in + i);
  b4 o;
  o.x = (__bf16)v.x; o.y = (__bf16)v.y; o.z = (__bf16)v.z; o.w = (__bf16)v.w;
  *reinterpret_cast<b4*>(out + i) = o;
}

__global__ __launch_bounds__(256) void cvt_w_kernel(const float* __restrict__ w0, const float* __restrict__ w1,
                                                    const float* __restrict__ w2, const float* __restrict__ w3,
                                                    __bf16* o0, __bf16* o1, __bf16* o2, __bf16* o3) {
  const float* in = blockIdx.y == 0 ? w0 : blockIdx.y == 1 ? w1 : blockIdx.y == 2 ? w2 : w3;
  __bf16* out     = blockIdx.y == 0 ? o0 : blockIdx.y == 1 ? o1 : blockIdx.y == 2 ? o2 : o3;
  int i = (blockIdx.x * 256 + threadIdx.x) * 4;
  float4 v = *reinterpret_cast<const float4*>(in + i);
  b4 o;
  o.x = (__bf16)v.x; o.y = (__bf16)v.y; o.z = (__bf16)v.z; o.w = (__bf16)v.w;
  *reinterpret_cast<b4*>(out + i) = o;
}

// ===================== GEMM core: C(128x128) = A * W^T =====================
__device__ __forceinline__ void gemm_core(const __bf16* __restrict__ A, const __bf16* __restrict__ W,
                                          int m0, int n0, __bf16* As, __bf16* Bs, f4 acc[4][4]) {
  const int t = threadIdx.x;
  const int lane = t & 63;
  const int w = t >> 6, wr = w >> 1, wc = w & 1;
  const f4 zero = {0.f, 0.f, 0.f, 0.f};
  #pragma unroll
  for (int mi = 0; mi < 4; ++mi)
    #pragma unroll
    for (int ni = 0; ni < 4; ++ni) acc[mi][ni] = zero;

  const char* Ab = (const char*)A;
  const char* Wb = (const char*)W;
  for (int kt = 0; kt < 512; kt += 64) {
    __syncthreads();
    #pragma unroll
    for (int i = 0; i < 4; ++i) {
      int o = i * 4096 + t * 16;
      int row = o >> 7, cb = o & 127;
      int scb = cb ^ ((row & 7) << 4);
      load_lds16(Ab + ((size_t)(m0 + row) * 512 + kt) * 2 + scb, (char*)As + o);
      load_lds16(Wb + ((size_t)(n0 + row) * 512 + kt) * 2 + scb, (char*)Bs + o);
    }
    __syncthreads();
    #pragma unroll
    for (int kk = 0; kk < 2; ++kk) {
      b8 af[4], bf[4];
      #pragma unroll
      for (int mi = 0; mi < 4; ++mi)
        af[mi] = lds_frag(As, wr * 64 + mi * 16 + (lane & 15), kk * 64 + ((lane >> 4) << 4));
      #pragma unroll
      for (int ni = 0; ni < 4; ++ni)
        bf[ni] = lds_frag(Bs, wc * 64 + ni * 16 + (lane & 15), kk * 64 + ((lane >> 4) << 4));
      #pragma unroll
      for (int mi = 0; mi < 4; ++mi)
        #pragma unroll
        for (int ni = 0; ni < 4; ++ni)
          acc[mi][ni] = mfma16(af[mi], bf[ni], acc[mi][ni]);
    }
  }
}

// ===================== QKV projection =====================
// z picks {Wq,Wk,Wv}. Writes [B,H,S,HD] bf16.
// Q pre-scaled by (1/sqrt(dk))*log2(e) so attention exp runs in base-2 domain.
__global__ __launch_bounds__(256) void gemm_qkv_kernel(
    const __bf16* __restrict__ xb,
    const __bf16* __restrict__ wq, const __bf16* __restrict__ wk, const __bf16* __restrict__ wv,
    const float* __restrict__ bq, const float* __restrict__ bk, const float* __restrict__ bv,
    __bf16* Qo, __bf16* Ko, __bf16* Vo) {
  __shared__ __bf16 As[128 * 64];
  __shared__ __bf16 Bs[128 * 64];
  int z = blockIdx.z;
  const __bf16* W = z == 0 ? wq : (z == 1 ? wk : wv);
  const float* bias = z == 0 ? bq : (z == 1 ? bk : bv);
  __bf16* out = z == 0 ? Qo : (z == 1 ? Ko : Vo);
  const float sc = (z == 0) ? 0.18033688011112042f : 1.0f;  // 0.125 * log2(e)
  int m0 = blockIdx.x * 128, n0 = blockIdx.y * 128;
  f4 acc[4][4];
  gemm_core(xb, W, m0, n0, As, Bs, acc);
  int t = threadIdx.x, lane = t & 63, w = t >> 6, wr = w >> 1, wc = w & 1;
  #pragma unroll
  for (int mi = 0; mi < 4; ++mi)
    #pragma unroll
    for (int ni = 0; ni < 4; ++ni)
      #pragma unroll
      for (int r = 0; r < 4; ++r) {
        int m = m0 + wr * 64 + mi * 16 + ((lane >> 4) << 2) + r;
        int n = n0 + wc * 64 + ni * 16 + (lane & 15);
        float v = (acc[mi][ni][r] + bias[n]) * sc;
        int b = m >> 11, s = m & 2047, h = n >> 6, hd = n & 63;
        out[(((size_t)(b * NHEAD + h)) * S_LEN + s) * HDIM + hd] = (__bf16)v;
      }
}

// ===================== output projection =====================
__global__ __launch_bounds__(256) void gemm_o_kernel(const __bf16* __restrict__ ctx,
                                                     const __bf16* __restrict__ wo,
                                                     const float* __restrict__ bo,
                                                     float* __restrict__ out) {
  __shared__ __bf16 As[128 * 64];
  __shared__ __bf16 Bs[128 * 64];
  int m0 = blockIdx.x * 128, n0 = blockIdx.y * 128;
  f4 acc[4][4];
  gemm_core(ctx, wo, m0, n0, As, Bs, acc);
  int t = threadIdx.x, lane = t & 63, w = t >> 6, wr = w >> 1, wc = w & 1;
  #pragma unroll
  for (int mi = 0; mi < 4; ++mi)
    #pragma unroll
    for (int ni = 0; ni < 4; ++ni)
      #pragma unroll
      for (int r = 0; r < 4; ++r) {
        int m = m0 + wr * 64 + mi * 16 + ((lane >> 4) << 2) + r;
        int n = n0 + wc * 64 + ni * 16 + (lane & 15);
        out[(size_t)m * D_DIM + n] = acc[mi][ni][r] + bo[n];
      }
}

// ===================== V transpose: [B,H,S,HD] -> [B,H,HD,S] =====================
__global__ __launch_bounds__(256) void transpose_v_kernel(const __bf16* __restrict__ V,
                                                          __bf16* __restrict__ Vt) {
  __shared__ __bf16 tile[64][72];
  int bh = blockIdx.y, s0 = blockIdx.x * 64;
  const __bf16* Vp = V + (size_t)bh * S_LEN * HDIM;
  __bf16* Vtp = Vt + (size_t)bh * HDIM * S_LEN;
  int t = threadIdx.x;
  #pragma unroll
  for (int i = 0; i < 4; ++i) {
    int q = t + i * 256;
    int row = q >> 4, c4 = (q & 15) * 4;
    b4 v = *reinterpret_cast<const b4*>(&Vp[(size_t)(s0 + row) * HDIM + c4]);
    *reinterpret_cast<b4*>(&tile[row][c4]) = v;
  }
  __syncthreads();
  #pragma unroll
  for (int i = 0; i < 4; ++i) {
    int q = t + i * 256;
    int d = q >> 4, s4 = (q & 15) * 4;
    b4 v;
    v.x = tile[s4 + 0][d]; v.y = tile[s4 + 1][d];
    v.z = tile[s4 + 2][d]; v.w = tile[s4 + 3][d];
    *reinterpret_cast<b4*>(&Vtp[(size_t)d * S_LEN + s0 + s4]) = v;
  }
}

// ===================== flash attention (kv-split-2, 8 waves) =====================
// 1-D grid 512 blocks, XCD-swizzled so each XCD owns 4 whole heads (K/V L2-resident).
// 512 threads = 8 waves: 4 q-subtiles (qs, 32 q) x 2 kv-halves (grp, 1024 kv each,
// private double-buffered K/V in one fused smem block). Swapped QK^T (A=K, B=Q);
// softmax in-register; P->bf16 via cvt_pk + permlane32_swap, ONE fragment at a
// time interleaved with its PV MFMAs; row-sum l via add tree (VALU — MFMA is
// the more loaded pipe); cross-half combines via shfl_xor (proven).
// kv loop unrolled x2 -> all ds_read offsets are compile-time immediates.
//
// smem layout (bytes): K tiles [grp*16384 + buf*8192, +8192) ; V at +32768.
#define NTG 16  // kv tiles per group: 1024 / 64

// Build PV B-fragment for one 16-k slot from C-layout f32 P regs base..base+7.
// v_permlane32_swap_b32: vdst.lanes[32:63] <-> vsrc.lanes[0:31]. swap(A0,B0):
//   lo lane: A0 = A0_own,     B0 = A0 from hi partner
//   hi lane: A0 = B0 from lo, B0 = B0_own
// -> fragment words [A0, A1, B0, B1] for both halves. (Producers are separate
// asm blocks; compiler scheduling provides the permlane hazard distance.)
#define MKFRAG(dst, st, base) do {                                   \
    unsigned int A0_ = pkbf((st)[(base)+0], (st)[(base)+1]);         \
    unsigned int A1_ = pkbf((st)[(base)+2], (st)[(base)+3]);         \
    unsigned int B0_ = pkbf((st)[(base)+4], (st)[(base)+5]);         \
    unsigned int B1_ = pkbf((st)[(base)+6], (st)[(base)+7]);         \
    asm("v_permlane32_swap_b32 %0, %1" : "+v"(A0_), "+v"(B0_));      \
    asm("v_permlane32_swap_b32 %0, %1" : "+v"(A1_), "+v"(B1_));      \
    u32x4 wv_; wv_.x = A0_; wv_.y = A1_; wv_.z = B0_; wv_.w = B1_;   \
    dst = __builtin_bit_cast(b8, wv_);                               \
  } while (0)

// One 64-kv tile. KO/VO are compile-time byte offsets of the K / V tiles.
#define TILE(KO, VO) do {                                                     \
    f16v t0 = Z16, t1 = Z16;                                                  \
    __builtin_amdgcn_s_setprio(1);                                            \
    _Pragma("unroll")                                                         \
    for (int ks = 0; ks < 4; ++ks) {                                          \
      b8 kf0 = *reinterpret_cast<const AS_LDS b8*>(sb + koff[ks] + (KO));     \
      b8 kf1 = *reinterpret_cast<const AS_LDS b8*>(sb + koff[ks] + (KO) + 4096); \
      t0 = mfma32(kf0, qf[ks], t0);                                           \
      t1 = mfma32(kf1, qf[ks], t1);                                           \
    }                                                                         \
    __builtin_amdgcn_s_setprio(0);                                            \
    float a0 = fmaxf(fmaxf(t0[0], t0[8]),  fmaxf(t1[0], t1[8]));              \
    float a1 = fmaxf(fmaxf(t0[1], t0[9]),  fmaxf(t1[1], t1[9]));              \
    float a2 = fmaxf(fmaxf(t0[2], t0[10]), fmaxf(t1[2], t1[10]));             \
    float a3 = fmaxf(fmaxf(t0[3], t0[11]), fmaxf(t1[3], t1[11]));             \
    float a4 = fmaxf(fmaxf(t0[4], t0[12]), fmaxf(t1[4], t1[12]));             \
    float a5 = fmaxf(fmaxf(t0[5], t0[13]), fmaxf(t1[5], t1[13]));             \
    float a6 = fmaxf(fmaxf(t0[6], t0[14]), fmaxf(t1[6], t1[14]));             \
    float a7 = fmaxf(fmaxf(t0[7], t0[15]), fmaxf(t1[7], t1[15]));             \
    float mx = fmaxf(fmaxf(fmaxf(a0, a1), fmaxf(a2, a3)),                     \
                     fmaxf(fmaxf(a4, a5), fmaxf(a6, a7)));                    \
    mx = xhalf_max(mx);                                                       \
    if (!__all(mx - mr <= 11.5f)) {                                           \
      float mn = fmaxf(mr, mx);                                               \
      float al = exp2v(mr - mn);                                              \
      mr = mn; lsum *= al; o0 *= al; o1 *= al;                                \
    }                                                                         \
    _Pragma("unroll")                                                         \
    for (int r = 0; r < 16; ++r) t0[r] = exp2v(t0[r] - mr);                   \
    _Pragma("unroll")                                                         \
    for (int r = 0; r < 16; ++r) t1[r] = exp2v(t1[r] - mr);                   \
    {                                                                         \
      float p0 = (t0[0] + t1[0]) + (t0[8]  + t1[8]);                          \
      float p1 = (t0[1] + t1[1]) + (t0[9]  + t1[9]);                          \
      float p2 = (t0[2] + t1[2]) + (t0[10] + t1[10]);                         \
      float p3 = (t0[3] + t1[3]) + (t0[11] + t1[11]);                         \
      float p4 = (t0[4] + t1[4]) + (t0[12] + t1[12]);                         \
      float p5 = (t0[5] + t1[5]) + (t0[13] + t1[13]);                         \
      float p6 = (t0[6] + t1[6]) + (t0[14] + t1[14]);                         \
      float p7 = (t0[7] + t1[7]) + (t0[15] + t1[15]);                         \
      lsum += ((p0 + p1) + (p2 + p3)) + ((p4 + p5) + (p6 + p7));              \
    }                                                                         \
    __builtin_amdgcn_s_setprio(1);                                            \
    _Pragma("unroll")                                                         \
    for (int ks = 0; ks < 4; ++ks) {                                          \
      b8 pa;                                                                  \
      if (ks == 0)      MKFRAG(pa, t0, 0);                                    \
      else if (ks == 1) MKFRAG(pa, t0, 8);                                    \
      else if (ks == 2) MKFRAG(pa, t1, 0);                                    \
      else              MKFRAG(pa, t1, 8);                                    \
      b8 vf0 = *reinterpret_cast<const AS_LDS b8*>(sb + koff[ks] + (VO));     \
      b8 vf1 = *reinterpret_cast<const AS_LDS b8*>(sb + koff[ks] + (VO) + 4096); \
      o0 = mfma32(vf0, pa, o0);                                               \
      o1 = mfma32(vf1, pa, o1);                                               \
    }                                                                         \
    __builtin_amdgcn_s_setprio(0);                                            \
  } while (0)

__global__ __launch_bounds__(512, 4) void attn_kernel(const __bf16* __restrict__ Q,
                                                      const __bf16* __restrict__ K,
                                                      const __bf16* __restrict__ Vt,
                                                      __bf16* __restrict__ ctx) {
  __shared__ char smem_[65536];
  int t = threadIdx.x, lane = t & 63, w = t >> 6;
  int lane31 = lane & 31, hi = lane >> 5;
  int grp = w >> 2, qs = w & 3, t256 = t & 255;

  // XCD swizzle: 512 blocks, 8 XCDs -> 64-block contiguous chunk per XCD
  // = 4 whole heads per XCD (16 q-tiles x same bh -> K/V L2-resident).
  int bid = blockIdx.x;
  int nid = (bid & 7) * 64 + (bid >> 3);
  int bh = nid >> 4, qtile = nid & 15;
  int b = bh >> 3, h = bh & 7;
  int q = qtile * 128 + qs * 32 + lane31;   // this lane's q row
  const __bf16* Qp = Q + (size_t)bh * S_LEN * HDIM;
  const __bf16* Kp = K + (size_t)bh * S_LEN * HDIM;
  const __bf16* Vp = Vt + (size_t)bh * HDIM * S_LEN;
  const int kv0 = grp * (S_LEN / 2);

  // Q fragments (B-operand: col=q=lane31, k=d=ks*16+hi*8+e). Q pre-scaled.
  b8 qf[4];
  #pragma unroll
  for (int ks = 0; ks < 4; ++ks)
    qf[ks] = *reinterpret_cast<const b8*>(&Qp[(size_t)q * HDIM + ks * 16 + hi * 8]);

  // 32-bit LDS base + per-ks fragment offsets (half1 = +4096 immediate since
  // (row+32)&7 == row&7). koff folds in grp*16384.
  const AS_LDS char* sb = (const AS_LDS char*)smem_;
  unsigned koff[4];
  #pragma unroll
  for (int ks = 0; ks < 4; ++ks) {
    int bc = hi * 16 + ks * 32;
    koff[ks] = grp * 16384 + lane31 * 128 + (bc ^ ((lane31 & 7) << 4));
  }

  // staging addresses (strength-reduced per iteration)
  int oA = t256 * 16, oB = 4096 + t256 * 16;
  int rA = oA >> 7, rB = oB >> 7;
  int sA = (oA & 127) ^ ((rA & 7) << 4), sB = (oB & 127) ^ ((rB & 7) << 4);
  const char* KgA = (const char*)Kp + (size_t)(kv0 + rA) * 128 + sA;   // += 8192/iter
  const char* KgB = (const char*)Kp + (size_t)(kv0 + rB) * 128 + sB;
  const char* VgA = (const char*)Vp + (size_t)rA * (S_LEN * 2) + (size_t)kv0 * 2 + sA;  // += 128/iter
  const char* VgB = (const char*)Vp + (size_t)rB * (S_LEN * 2) + (size_t)kv0 * 2 + sB;

  const f16v Z16 = {0,0,0,0,0,0,0,0,0,0,0,0,0,0,0,0};
  f16v o0 = Z16, o1 = Z16;   // O^T accum: rows d (0-31 / 32-63), col q
  float mr = -1e30f, lsum = 0.f;

  auto stage = [&](int buf) {
    char* ldsK = smem_ + grp * 16384 + buf * 8192;
    load_lds16(KgA, ldsK + oA);
    load_lds16(KgB, ldsK + oB);
    load_lds16(VgA, ldsK + 32768 + oA);
    load_lds16(VgB, ldsK + 32768 + oB);
    KgA += 8192; KgB += 8192; VgA += 128; VgB += 128;
  };

  stage(0);
  __syncthreads();

  #pragma unroll 1
  for (int it2 = 0; it2 < NTG / 2; ++it2) {
    stage(1);
    TILE(0, 32768);
    __syncthreads();
    if (it2 < NTG / 2 - 1) stage(0);
    TILE(8192, 40960);
    __syncthreads();
  }

  // ---- merge the two kv-halves (grp1 -> LDS -> grp0), then write ctx ----
  float l_own = xhalf_add(lsum);      // both halves' kv columns combined
  float* OL = (float*)smem_;          // [4 qs][64 d][32 q] f32 = 32 KiB (staging dead)
  float* ML = OL + 8192;              // m[4][32] then l[4][32]
  if (grp == 1) {
    #pragma unroll
    for (int g = 0; g < 4; ++g)
      #pragma unroll
      for (int j = 0; j < 4; ++j) {
        int d = 8 * g + 4 * hi + j;
        OL[(qs * 64 + d) * 32 + lane31]      = o0[4 * g + j];
        OL[(qs * 64 + 32 + d) * 32 + lane31] = o1[4 * g + j];
      }
    if (hi == 0) { ML[qs * 32 + lane31] = mr; ML[128 + qs * 32 + lane31] = l_own; }
  }
  __syncthreads();
  if (grp == 0) {
    float m1 = ML[qs * 32 + lane31], l1 = ML[128 + qs * 32 + lane31];
    float mm = fmaxf(mr, m1);
    float s0 = exp2v(mr - mm), s1 = exp2v(m1 - mm);
    float inv = 1.0f / (l_own * s0 + l1 * s1);
    __bf16* cp = ctx + (size_t)b * S_LEN * D_DIM + (size_t)q * D_DIM + (size_t)h * HDIM;
    #pragma unroll
    for (int g = 0; g < 4; ++g) {
      b4 v0, v1;
      #pragma unroll
      for (int j = 0; j < 4; ++j) {
        int d = 8 * g + 4 * hi + j;
        v0[j] = (__bf16)((o0[4 * g + j] * s0 + OL[(qs * 64 + d) * 32 + lane31] * s1) * inv);
        v1[j] = (__bf16)((o1[4 * g + j] * s0 + OL[(qs * 64 + 32 + d) * 32 + lane31] * s1) * inv);
      }
      int d0 = 8 * g + 4 * hi;
      *reinterpret_cast<b4*>(cp + d0)      = v0;
      *reinterpret_cast<b4*>(cp + 32 + d0) = v1;
    }
  }
}

// ===================== launch =====================
extern "C" void kernel_launch(void* const* d_in, const int* in_sizes, int n_in,
                              void* d_out, int out_size, void* d_ws, size_t ws_size,
                              hipStream_t stream) {
  const float* x  = (const float*)d_in[0];
  const float* Wq = (const float*)d_in[1];
  const float* bq = (const float*)d_in[2];
  const float* Wk = (const float*)d_in[3];
  const float* bk = (const float*)d_in[4];
  const float* Wv = (const float*)d_in[5];
  const float* bv = (const float*)d_in[6];
  const float* Wo = (const float*)d_in[7];
  const float* bo = (const float*)d_in[8];
  float* out = (float*)d_out;

  char* ws = (char*)d_ws;
  __bf16* xb   = (__bf16*)(ws);                               // 8192*512
  __bf16* wqb  = xb  + 4194304;                               // 512*512
  __bf16* wkb  = wqb + 262144;
  __bf16* wvb  = wkb + 262144;
  __bf16* wob  = wvb + 262144;
  __bf16* Qb   = wob + 262144;                                // 4*8*2048*64
  __bf16* Kb   = Qb  + 4194304;
  __bf16* Vb   = Kb  + 4194304;
  __bf16* Vtb  = Vb  + 4194304;
  __bf16* ctxb = xb;  // reuse (x dead after QKV)

  cvt_kernel<<<dim3(4096), dim3(256), 0, stream>>>(x, xb);
  cvt_w_kernel<<<dim3(256, 4), dim3(256), 0, stream>>>(Wq, Wk, Wv, Wo, wqb, wkb, wvb, wob);
  gemm_qkv_kernel<<<dim3(64, 4, 3), dim3(256), 0, stream>>>(xb, wqb, wkb, wvb, bq, bk, bv, Qb, Kb, Vb);
  transpose_v_kernel<<<dim3(32, 32), dim3(256), 0, stream>>>(Vb, Vtb);
  attn_kernel<<<dim3(512), dim3(512), 0, stream>>>(Qb, Kb, Vtb, ctxb);
  gemm_o_kernel<<<dim3(64, 4), dim3(256), 0, stream>>>(ctxb, wob, bo, out);
}